// Round 2
// baseline (238.830 us; speedup 1.0000x reference)
//
#include <hip/hip_runtime.h>

#define BATCH   8
#define LENGTH  4096
#define IN_DIM  512
#define STATE   256
#define OUT_DIM 512
#define NC      256
#define LC      16

typedef __attribute__((ext_vector_type(8))) short bf16x8;
typedef __attribute__((ext_vector_type(4))) float f32x4;
typedef __attribute__((ext_vector_type(4))) unsigned short u16x4;

union FragU { bf16x8 v; unsigned u[4]; };

__device__ __forceinline__ unsigned short bf16_rne(float v) {
    unsigned u = __builtin_bit_cast(unsigned, v);
    unsigned r = (u + 0x7FFFu + ((u >> 16) & 1u)) >> 16;
    return (unsigned short)r;
}
__device__ __forceinline__ float bf16_f(unsigned short h) {
    unsigned u = ((unsigned)h) << 16;
    return __builtin_bit_cast(float, u);
}

// ---------------------------------------------------------------------------
// Merged weight split+transpose: B[512][256] and C[256][512] fp32 ->
// hi/lo bf16 planes [N][K] (RNE).
// ---------------------------------------------------------------------------
__global__ __launch_bounds__(256) void split_weights(
    const float* __restrict__ B, const float* __restrict__ C,
    unsigned short* __restrict__ Bhi, unsigned short* __restrict__ Blo,
    unsigned short* __restrict__ Chi, unsigned short* __restrict__ Clo)
{
    int id = blockIdx.x * 256 + threadIdx.x;
    if (id < IN_DIM * STATE) {
        int k = id & (IN_DIM - 1), n = id >> 9;      // Bt[n=state][k=in]
        float v = B[(size_t)k * STATE + n];
        unsigned short h = bf16_rne(v);
        Bhi[id] = h;
        Blo[id] = bf16_rne(v - bf16_f(h));
    } else {
        int id2 = id - IN_DIM * STATE;
        int k = id2 & (STATE - 1), n = id2 >> 8;     // Ct[n=out][k=state]
        float v = C[(size_t)k * OUT_DIM + n];
        unsigned short h = bf16_rne(v);
        Chi[id2] = h;
        Clo[id2] = bf16_rne(v - bf16_f(h));
    }
}

// ---------------------------------------------------------------------------
// GEMM1: split-bf16 MFMA GEMM, A read as fp32 (in-register hi/lo split).
// Tile 128x128, BK=32, 8 waves (4Mx2N), LDS 2x32KB double buffer,
// raw s_barrier + vmcnt(4) counted prefetch.
// NEW: T1 XCD-aware block swizzle (nwg%8==0 -> simple form bijective):
// consecutive logical tiles (both n-blocks of one m-band) land on the SAME
// XCD so the second read of a u row hits that XCD's L2, not L3.
// ---------------------------------------------------------------------------
__global__ __launch_bounds__(512, 4) void gemm_dbuf(
    const float* __restrict__ Af, const unsigned short* __restrict__ Bthi,
    const unsigned short* __restrict__ Btlo, float* __restrict__ Cc,
    int N_, int K)
{
    __shared__ unsigned short lds[2 * 16384];   // 64 KB

    const int tid  = threadIdx.x;
    const int wave = tid >> 6;
    const int lane = tid & 63;

    // XCD swizzle: original flat id round-robins XCDs; give each XCD a
    // contiguous chunk of logical tile space.
    const unsigned nwgx = gridDim.x;
    const unsigned flat = blockIdx.y * nwgx + blockIdx.x;
    const unsigned cpx  = (nwgx * gridDim.y) >> 3;
    const unsigned swz  = (flat & 7u) * cpx + (flat >> 3);
    const int n0 = (int)(swz % nwgx) * 128;
    const int m0 = (int)(swz / nwgx) * 128;

    // --- staging descriptors: 32 wave-instructions of 1KB; 4 per wave ---
    const char* gp[4];
    int ldsoff[4], gstep[4];
    #pragma unroll
    for (int t = 0; t < 4; ++t) {
        int gi = wave * 4 + t;
        if (gi < 16) {          // A plane: 1024 slots (16 KB)
            int p = gi * 64 + lane;
            int row = p >> 3, s = p & 7;
            int l = s ^ (row & 7);
            gp[t] = (const char*)(Af + (size_t)(m0 + row) * K + l * 4);
            gstep[t] = 32 * 4;              // BK fp32
            ldsoff[t] = gi * 512;
        } else {                // B planes: 512 slots each (8 KB)
            int q2 = (gi - 16) >> 3;        // 0 = hi, 1 = lo
            int pi = gi & 7;
            int p = pi * 64 + lane;
            int row = p >> 2, s = p & 3;
            int l = s ^ ((row >> 1) & 3);
            const unsigned short* base = q2 ? Btlo : Bthi;
            gp[t] = (const char*)(base + (size_t)(n0 + row) * K + l * 8);
            gstep[t] = 32 * 2;              // BK bf16
            ldsoff[t] = 8192 + q2 * 4096 + pi * 512;
        }
    }

    const int r = lane & 15, q = lane >> 4;
    const int wm = (wave >> 1) * 32, wn = (wave & 1) * 64;

    int aoff[2][2], boff[4];
    #pragma unroll
    for (int i = 0; i < 2; ++i) {
        int row = wm + i * 16 + r;
        #pragma unroll
        for (int h = 0; h < 2; ++h)
            aoff[i][h] = row * 64 + ((2 * q + h) ^ (row & 7)) * 8;
    }
    #pragma unroll
    for (int j = 0; j < 4; ++j) {
        int row = wn + j * 16 + r;
        boff[j] = row * 32 + (q ^ ((row >> 1) & 3)) * 8;
    }

    f32x4 acc[2][4];
    #pragma unroll
    for (int i = 0; i < 2; ++i)
        #pragma unroll
        for (int j = 0; j < 4; ++j)
            acc[i][j] = (f32x4){0.f, 0.f, 0.f, 0.f};

    #pragma unroll
    for (int t = 0; t < 4; ++t) {
        __builtin_amdgcn_global_load_lds(
            (const __attribute__((address_space(1))) unsigned*)(gp[t]),
            (__attribute__((address_space(3))) unsigned*)(&lds[ldsoff[t]]),
            16, 0, 0);
        gp[t] += gstep[t];
    }

    const int nit = K >> 5;
    for (int it = 0; it < nit; ++it) {
        asm volatile("" ::: "memory");
        __builtin_amdgcn_s_barrier();
        asm volatile("" ::: "memory");
        if (it + 1 < nit) {
            const int bb = ((it + 1) & 1) * 16384;
            #pragma unroll
            for (int t = 0; t < 4; ++t) {
                __builtin_amdgcn_global_load_lds(
                    (const __attribute__((address_space(1))) unsigned*)(gp[t]),
                    (__attribute__((address_space(3))) unsigned*)(&lds[bb + ldsoff[t]]),
                    16, 0, 0);
                gp[t] += gstep[t];
            }
            __builtin_amdgcn_s_waitcnt(0x0F74);   // vmcnt(4)
        } else {
            __builtin_amdgcn_s_waitcnt(0x0F70);   // vmcnt(0)
        }
        asm volatile("" ::: "memory");
        __builtin_amdgcn_s_barrier();
        asm volatile("" ::: "memory");

        const unsigned short* buf = &lds[(it & 1) * 16384];

        FragU ahi[2], alo[2];
        #pragma unroll
        for (int i = 0; i < 2; ++i) {
            #pragma unroll
            for (int h = 0; h < 2; ++h) {
                float4 f = *(const float4*)(buf + aoff[i][h]);
                unsigned bx = __builtin_bit_cast(unsigned, f.x);
                unsigned by = __builtin_bit_cast(unsigned, f.y);
                unsigned bz = __builtin_bit_cast(unsigned, f.z);
                unsigned bw = __builtin_bit_cast(unsigned, f.w);
                ahi[i].u[h * 2]     = __builtin_amdgcn_perm(by, bx, 0x07060302);
                ahi[i].u[h * 2 + 1] = __builtin_amdgcn_perm(bw, bz, 0x07060302);
                float lx = f.x - __builtin_bit_cast(float, bx & 0xFFFF0000u);
                float ly = f.y - __builtin_bit_cast(float, by & 0xFFFF0000u);
                float lz = f.z - __builtin_bit_cast(float, bz & 0xFFFF0000u);
                float lw = f.w - __builtin_bit_cast(float, bw & 0xFFFF0000u);
                alo[i].u[h * 2]     = __builtin_amdgcn_perm(
                    __builtin_bit_cast(unsigned, ly), __builtin_bit_cast(unsigned, lx), 0x07060302);
                alo[i].u[h * 2 + 1] = __builtin_amdgcn_perm(
                    __builtin_bit_cast(unsigned, lw), __builtin_bit_cast(unsigned, lz), 0x07060302);
            }
        }
        FragU bhi[4], blo[4];
        #pragma unroll
        for (int j = 0; j < 4; ++j) {
            bhi[j].v = *(const bf16x8*)(buf +  8192 + boff[j]);
            blo[j].v = *(const bf16x8*)(buf + 12288 + boff[j]);
        }
        #pragma unroll
        for (int i = 0; i < 2; ++i)
            #pragma unroll
            for (int j = 0; j < 4; ++j) {
                acc[i][j] = __builtin_amdgcn_mfma_f32_16x16x32_bf16(ahi[i].v, bhi[j].v, acc[i][j], 0, 0, 0);
                acc[i][j] = __builtin_amdgcn_mfma_f32_16x16x32_bf16(alo[i].v, bhi[j].v, acc[i][j], 0, 0, 0);
                acc[i][j] = __builtin_amdgcn_mfma_f32_16x16x32_bf16(ahi[i].v, blo[j].v, acc[i][j], 0, 0, 0);
            }
    }

    #pragma unroll
    for (int i = 0; i < 2; ++i) {
        #pragma unroll
        for (int reg = 0; reg < 4; ++reg) {
            int mg = m0 + wm + i * 16 + q * 4 + reg;
            float* dst = Cc + (size_t)mg * N_ + n0 + wn + r;
            dst[0]  = acc[i][0][reg];
            dst[16] = acc[i][1][reg];
            dst[32] = acc[i][2][reg];
            dst[48] = acc[i][3][reg];
        }
    }
}

// ---------------------------------------------------------------------------
// GEMM2: all operands pre-split bf16 planes. Same schedule as GEMM1, no
// fp32 split (A = x planes from scan_apply). + T1 XCD swizzle.
// ---------------------------------------------------------------------------
__global__ __launch_bounds__(512, 4) void gemm_presplit(
    const unsigned short* __restrict__ Athi, const unsigned short* __restrict__ Atlo,
    const unsigned short* __restrict__ Bthi, const unsigned short* __restrict__ Btlo,
    float* __restrict__ Cc, int N_, int K)
{
    __shared__ unsigned short lds[2 * 16384];   // 64 KB

    const int tid  = threadIdx.x;
    const int wave = tid >> 6;
    const int lane = tid & 63;

    const unsigned nwgx = gridDim.x;
    const unsigned flat = blockIdx.y * nwgx + blockIdx.x;
    const unsigned cpx  = (nwgx * gridDim.y) >> 3;
    const unsigned swz  = (flat & 7u) * cpx + (flat >> 3);
    const int n0 = (int)(swz % nwgx) * 128;
    const int m0 = (int)(swz / nwgx) * 128;

    const char* gp[4];
    int ldsoff[4];
    #pragma unroll
    for (int t = 0; t < 4; ++t) {
        int gi = wave * 4 + t;
        int plane = gi >> 3;                // 0=Ahi 1=Alo 2=Bhi 3=Blo
        int pi = gi & 7;
        int p = pi * 64 + lane;
        int row = p >> 2, s = p & 3;
        int l = s ^ ((row >> 1) & 3);
        const unsigned short* base =
            (plane == 0) ? Athi : (plane == 1) ? Atlo : (plane == 2) ? Bthi : Btlo;
        int r0 = (plane < 2) ? m0 : n0;
        gp[t] = (const char*)(base + (size_t)(r0 + row) * K + l * 8);
        ldsoff[t] = plane * 4096 + pi * 512;
    }

    const int r = lane & 15, q = lane >> 4;
    const int wm = (wave >> 2) * 64, wn = (wave & 3) * 32;

    int aoff[4], boff[2];
    #pragma unroll
    for (int i = 0; i < 4; ++i) {
        int row = wm + i * 16 + r;
        aoff[i] = row * 32 + (q ^ ((row >> 1) & 3)) * 8;
    }
    #pragma unroll
    for (int j = 0; j < 2; ++j) {
        int row = wn + j * 16 + r;
        boff[j] = row * 32 + (q ^ ((row >> 1) & 3)) * 8;
    }

    f32x4 acc[4][2];
    #pragma unroll
    for (int i = 0; i < 4; ++i)
        #pragma unroll
        for (int j = 0; j < 2; ++j)
            acc[i][j] = (f32x4){0.f, 0.f, 0.f, 0.f};

    #pragma unroll
    for (int t = 0; t < 4; ++t) {
        __builtin_amdgcn_global_load_lds(
            (const __attribute__((address_space(1))) unsigned*)(gp[t]),
            (__attribute__((address_space(3))) unsigned*)(&lds[ldsoff[t]]),
            16, 0, 0);
        gp[t] += 64;                        // BK bf16 = 64 B
    }

    const int nit = K >> 5;
    for (int it = 0; it < nit; ++it) {
        asm volatile("" ::: "memory");
        __builtin_amdgcn_s_barrier();
        asm volatile("" ::: "memory");
        if (it + 1 < nit) {
            const int bb = ((it + 1) & 1) * 16384;
            #pragma unroll
            for (int t = 0; t < 4; ++t) {
                __builtin_amdgcn_global_load_lds(
                    (const __attribute__((address_space(1))) unsigned*)(gp[t]),
                    (__attribute__((address_space(3))) unsigned*)(&lds[bb + ldsoff[t]]),
                    16, 0, 0);
                gp[t] += 64;
            }
            __builtin_amdgcn_s_waitcnt(0x0F74);   // vmcnt(4)
        } else {
            __builtin_amdgcn_s_waitcnt(0x0F70);   // vmcnt(0)
        }
        asm volatile("" ::: "memory");
        __builtin_amdgcn_s_barrier();
        asm volatile("" ::: "memory");

        const unsigned short* buf = &lds[(it & 1) * 16384];

        FragU ahi[4], alo[4];
        #pragma unroll
        for (int i = 0; i < 4; ++i) {
            ahi[i].v = *(const bf16x8*)(buf +        aoff[i]);
            alo[i].v = *(const bf16x8*)(buf + 4096 + aoff[i]);
        }
        FragU bhi[2], blo[2];
        #pragma unroll
        for (int j = 0; j < 2; ++j) {
            bhi[j].v = *(const bf16x8*)(buf +  8192 + boff[j]);
            blo[j].v = *(const bf16x8*)(buf + 12288 + boff[j]);
        }
        #pragma unroll
        for (int i = 0; i < 4; ++i)
            #pragma unroll
            for (int j = 0; j < 2; ++j) {
                acc[i][j] = __builtin_amdgcn_mfma_f32_16x16x32_bf16(ahi[i].v, bhi[j].v, acc[i][j], 0, 0, 0);
                acc[i][j] = __builtin_amdgcn_mfma_f32_16x16x32_bf16(alo[i].v, bhi[j].v, acc[i][j], 0, 0, 0);
                acc[i][j] = __builtin_amdgcn_mfma_f32_16x16x32_bf16(ahi[i].v, blo[j].v, acc[i][j], 0, 0, 0);
            }
    }

    #pragma unroll
    for (int i = 0; i < 4; ++i) {
        #pragma unroll
        for (int reg = 0; reg < 4; ++reg) {
            int mg = m0 + wm + i * 16 + q * 4 + reg;
            float* dst = Cc + (size_t)mg * N_ + n0 + wn + r;
            dst[0]  = acc[i][0][reg];
            dst[16] = acc[i][1][reg];
        }
    }
}

// ---------------------------------------------------------------------------
// Scan phase A: per-chunk carry, LC=16, one wave per (b,chunk), float4/thread.
// 2048 blocks = 8 waves/CU; 16 independent 1KB wave-loads in flight.
// ---------------------------------------------------------------------------
__global__ __launch_bounds__(64) void scan_carry(
    const float* __restrict__ uB, const float* __restrict__ A,
    float* __restrict__ carry)
{
    const int b = blockIdx.x;
    const int c = blockIdx.y;
    const int t = threadIdx.x;              // states n = 4t..4t+3
    const float4 a = *(const float4*)(A + 4 * t);
    const float4* p = (const float4*)(uB + ((size_t)b * LENGTH + (size_t)c * LC) * STATE) + t;
    float4 s = make_float4(0.f, 0.f, 0.f, 0.f);
    #pragma unroll
    for (int j = 0; j < LC; ++j) {
        float4 v = p[(size_t)j * (STATE / 4)];
        s.x = fmaf(a.x, s.x, v.x);
        s.y = fmaf(a.y, s.y, v.y);
        s.z = fmaf(a.z, s.z, v.z);
        s.w = fmaf(a.w, s.w, v.w);
    }
    *((float4*)(carry + ((size_t)b * NC + c) * STATE) + t) = s;
}

// ---------------------------------------------------------------------------
// Scan phase B (fused combine+apply): rebuild entry state from <=255 carries
// (loads independent of the FMA chain -> prefetchable; carry is 2MB, L2-hot),
// then 16 apply steps writing x as trunc-split hi/lo bf16 planes (ushort4).
// ---------------------------------------------------------------------------
__global__ __launch_bounds__(64) void scan_apply(
    const float* __restrict__ uB, const float* __restrict__ A,
    const float* __restrict__ carry, const float* __restrict__ x0,
    unsigned short* __restrict__ xhi, unsigned short* __restrict__ xlo,
    float* __restrict__ x_last)
{
    const int b = blockIdx.x;
    const int c = blockIdx.y;
    const int t = threadIdx.x;              // states n = 4t..4t+3
    const float4 a = *(const float4*)(A + 4 * t);
    float4 aL = a;
    #pragma unroll
    for (int k = 0; k < 4; ++k) {           // aL = a^16
        aL.x *= aL.x; aL.y *= aL.y; aL.z *= aL.z; aL.w *= aL.w;
    }

    float4 s = *((const float4*)(x0 + (size_t)b * STATE) + t);
    const float4* cr = (const float4*)(carry + (size_t)b * NC * STATE) + t;
    for (int d = 0; d < c; ++d) {
        float4 v = cr[(size_t)d * (STATE / 4)];
        s.x = fmaf(aL.x, s.x, v.x);
        s.y = fmaf(aL.y, s.y, v.y);
        s.z = fmaf(aL.z, s.z, v.z);
        s.w = fmaf(aL.w, s.w, v.w);
    }

    const size_t base = ((size_t)b * LENGTH + (size_t)c * LC) * STATE;
    const float4* p = (const float4*)(uB + base) + t;
    u16x4* qh = (u16x4*)(xhi + base) + t;
    u16x4* ql = (u16x4*)(xlo + base) + t;
    #pragma unroll
    for (int j = 0; j < LC; ++j) {
        float4 v = p[(size_t)j * (STATE / 4)];
        s.x = fmaf(a.x, s.x, v.x);
        s.y = fmaf(a.y, s.y, v.y);
        s.z = fmaf(a.z, s.z, v.z);
        s.w = fmaf(a.w, s.w, v.w);
        u16x4 hh, ll;
        unsigned ux = __builtin_bit_cast(unsigned, s.x);
        unsigned uy = __builtin_bit_cast(unsigned, s.y);
        unsigned uz = __builtin_bit_cast(unsigned, s.z);
        unsigned uw = __builtin_bit_cast(unsigned, s.w);
        hh[0] = (unsigned short)(ux >> 16);
        hh[1] = (unsigned short)(uy >> 16);
        hh[2] = (unsigned short)(uz >> 16);
        hh[3] = (unsigned short)(uw >> 16);
        float lx = s.x - __builtin_bit_cast(float, ux & 0xFFFF0000u);
        float ly = s.y - __builtin_bit_cast(float, uy & 0xFFFF0000u);
        float lz = s.z - __builtin_bit_cast(float, uz & 0xFFFF0000u);
        float lw = s.w - __builtin_bit_cast(float, uw & 0xFFFF0000u);
        ll[0] = (unsigned short)(__builtin_bit_cast(unsigned, lx) >> 16);
        ll[1] = (unsigned short)(__builtin_bit_cast(unsigned, ly) >> 16);
        ll[2] = (unsigned short)(__builtin_bit_cast(unsigned, lz) >> 16);
        ll[3] = (unsigned short)(__builtin_bit_cast(unsigned, lw) >> 16);
        qh[(size_t)j * (STATE / 4)] = hh;
        ql[(size_t)j * (STATE / 4)] = ll;
    }
    if (c == NC - 1)
        *((float4*)(x_last + (size_t)b * STATE) + t) = s;
}

// ---------------------------------------------------------------------------
extern "C" void kernel_launch(void* const* d_in, const int* in_sizes, int n_in,
                              void* d_out, int out_size, void* d_ws, size_t ws_size,
                              hipStream_t stream)
{
    const float* u  = (const float*)d_in[0];   // [8,4096,512]
    const float* x0 = (const float*)d_in[1];   // [8,256]
    const float* A  = (const float*)d_in[2];   // [256]
    const float* B  = (const float*)d_in[3];   // [512,256]
    const float* C  = (const float*)d_in[4];   // [256,512]

    const size_t MB = 1024 * 1024;
    char* ws = (char*)d_ws;

    unsigned short* xhi = (unsigned short*)(ws);                // [M,256] bf16, 16 MB
    unsigned short* xlo = (unsigned short*)(ws + 16 * MB);      // [M,256] bf16, 16 MB
    float* carry = (float*)(ws + 32 * MB);                      // [8,256,256] fp32, 2 MB
    unsigned short* Bt_hi = (unsigned short*)(ws + 34 * MB);                // 256 KB
    unsigned short* Bt_lo = (unsigned short*)(ws + 34 * MB + 256 * 1024);   // 256 KB
    unsigned short* Ct_hi = (unsigned short*)(ws + 34 * MB + 512 * 1024);   // 256 KB
    unsigned short* Ct_lo = (unsigned short*)(ws + 34 * MB + 768 * 1024);   // 256 KB

    float* y      = (float*)d_out;                             // [8,4096,512] = 64 MB
    float* x_last = y + (size_t)BATCH * LENGTH * OUT_DIM;      // [8,256]
    // uB parks in the upper half of y's region; dead before GEMM2 writes y.
    float* uB     = (float*)((char*)d_out + 32 * MB);          // [M,256] = 32 MB

    const int M = BATCH * LENGTH;   // 32768

    // 1. split+transpose both weights to bf16 hi/lo planes
    split_weights<<<dim3((IN_DIM * STATE + STATE * OUT_DIM) / 256), dim3(256), 0, stream>>>(
        B, C, Bt_hi, Bt_lo, Ct_hi, Ct_lo);

    // 2. GEMM1: uB[M,256] = u[M,512] @ B
    gemm_dbuf<<<dim3(STATE / 128, M / 128), dim3(512), 0, stream>>>(
        u, Bt_hi, Bt_lo, uB, STATE, IN_DIM);

    // 3. chunked scan (fp32 exact), LC=16: 2048 one-wave blocks, float4/thread
    scan_carry<<<dim3(BATCH, NC), dim3(64), 0, stream>>>(uB, A, carry);
    scan_apply<<<dim3(BATCH, NC), dim3(64), 0, stream>>>(uB, A, carry, x0, xhi, xlo, x_last);

    // 4. GEMM2: y[M,512] = x[M,256] @ C  (all operands pre-split bf16)
    gemm_presplit<<<dim3(OUT_DIM / 128, M / 128), dim3(512), 0, stream>>>(
        xhi, xlo, Ct_hi, Ct_lo, y, OUT_DIM, STATE);
}

// Round 3
// 208.689 us; speedup vs baseline: 1.1444x; 1.1444x over previous
//
#include <hip/hip_runtime.h>

#define BATCH   8
#define LENGTH  4096
#define IN_DIM  512
#define STATE   256
#define OUT_DIM 512
#define NC      256
#define LC      16

typedef __attribute__((ext_vector_type(8))) short bf16x8;
typedef __attribute__((ext_vector_type(4))) float f32x4;
typedef __attribute__((ext_vector_type(4))) unsigned short u16x4;

union FragU { bf16x8 v; unsigned u[4]; };

__device__ __forceinline__ unsigned short bf16_rne(float v) {
    unsigned u = __builtin_bit_cast(unsigned, v);
    unsigned r = (u + 0x7FFFu + ((u >> 16) & 1u)) >> 16;
    return (unsigned short)r;
}
__device__ __forceinline__ float bf16_f(unsigned short h) {
    unsigned u = ((unsigned)h) << 16;
    return __builtin_bit_cast(float, u);
}

// ---------------------------------------------------------------------------
// Merged weight split+transpose: B[512][256] and C[256][512] fp32 ->
// hi/lo bf16 planes [N][K] (RNE).
// ---------------------------------------------------------------------------
__global__ __launch_bounds__(256) void split_weights(
    const float* __restrict__ B, const float* __restrict__ C,
    unsigned short* __restrict__ Bhi, unsigned short* __restrict__ Blo,
    unsigned short* __restrict__ Chi, unsigned short* __restrict__ Clo)
{
    int id = blockIdx.x * 256 + threadIdx.x;
    if (id < IN_DIM * STATE) {
        int k = id & (IN_DIM - 1), n = id >> 9;      // Bt[n=state][k=in]
        float v = B[(size_t)k * STATE + n];
        unsigned short h = bf16_rne(v);
        Bhi[id] = h;
        Blo[id] = bf16_rne(v - bf16_f(h));
    } else {
        int id2 = id - IN_DIM * STATE;
        int k = id2 & (STATE - 1), n = id2 >> 8;     // Ct[n=out][k=state]
        float v = C[(size_t)k * OUT_DIM + n];
        unsigned short h = bf16_rne(v);
        Chi[id2] = h;
        Clo[id2] = bf16_rne(v - bf16_f(h));
    }
}

// ---------------------------------------------------------------------------
// GEMM1: split-bf16 MFMA GEMM, A read as fp32 (in-register hi/lo split).
// Tile 128x128, BK=32, 8 waves (4Mx2N), LDS 2x32KB double buffer,
// raw s_barrier + vmcnt(4) counted prefetch. NO XCD swizzle: with
// gridDim.x=2 the default flat order already places both n-tiles of an
// m-band adjacently (same XCD) -> swizzling scattered them (round-2 lesson).
// ---------------------------------------------------------------------------
__global__ __launch_bounds__(512, 4) void gemm_dbuf(
    const float* __restrict__ Af, const unsigned short* __restrict__ Bthi,
    const unsigned short* __restrict__ Btlo, float* __restrict__ Cc,
    int N_, int K)
{
    __shared__ unsigned short lds[2 * 16384];   // 64 KB

    const int tid  = threadIdx.x;
    const int wave = tid >> 6;
    const int lane = tid & 63;
    const int n0 = blockIdx.x * 128;
    const int m0 = blockIdx.y * 128;

    // --- staging descriptors: 32 wave-instructions of 1KB; 4 per wave ---
    const char* gp[4];
    int ldsoff[4], gstep[4];
    #pragma unroll
    for (int t = 0; t < 4; ++t) {
        int gi = wave * 4 + t;
        if (gi < 16) {          // A plane: 1024 slots (16 KB)
            int p = gi * 64 + lane;
            int row = p >> 3, s = p & 7;
            int l = s ^ (row & 7);
            gp[t] = (const char*)(Af + (size_t)(m0 + row) * K + l * 4);
            gstep[t] = 32 * 4;              // BK fp32
            ldsoff[t] = gi * 512;
        } else {                // B planes: 512 slots each (8 KB)
            int q2 = (gi - 16) >> 3;        // 0 = hi, 1 = lo
            int pi = gi & 7;
            int p = pi * 64 + lane;
            int row = p >> 2, s = p & 3;
            int l = s ^ ((row >> 1) & 3);
            const unsigned short* base = q2 ? Btlo : Bthi;
            gp[t] = (const char*)(base + (size_t)(n0 + row) * K + l * 8);
            gstep[t] = 32 * 2;              // BK bf16
            ldsoff[t] = 8192 + q2 * 4096 + pi * 512;
        }
    }

    const int r = lane & 15, q = lane >> 4;
    const int wm = (wave >> 1) * 32, wn = (wave & 1) * 64;

    int aoff[2][2], boff[4];
    #pragma unroll
    for (int i = 0; i < 2; ++i) {
        int row = wm + i * 16 + r;
        #pragma unroll
        for (int h = 0; h < 2; ++h)
            aoff[i][h] = row * 64 + ((2 * q + h) ^ (row & 7)) * 8;
    }
    #pragma unroll
    for (int j = 0; j < 4; ++j) {
        int row = wn + j * 16 + r;
        boff[j] = row * 32 + (q ^ ((row >> 1) & 3)) * 8;
    }

    f32x4 acc[2][4];
    #pragma unroll
    for (int i = 0; i < 2; ++i)
        #pragma unroll
        for (int j = 0; j < 4; ++j)
            acc[i][j] = (f32x4){0.f, 0.f, 0.f, 0.f};

    #pragma unroll
    for (int t = 0; t < 4; ++t) {
        __builtin_amdgcn_global_load_lds(
            (const __attribute__((address_space(1))) unsigned*)(gp[t]),
            (__attribute__((address_space(3))) unsigned*)(&lds[ldsoff[t]]),
            16, 0, 0);
        gp[t] += gstep[t];
    }

    const int nit = K >> 5;
    for (int it = 0; it < nit; ++it) {
        asm volatile("" ::: "memory");
        __builtin_amdgcn_s_barrier();
        asm volatile("" ::: "memory");
        if (it + 1 < nit) {
            const int bb = ((it + 1) & 1) * 16384;
            #pragma unroll
            for (int t = 0; t < 4; ++t) {
                __builtin_amdgcn_global_load_lds(
                    (const __attribute__((address_space(1))) unsigned*)(gp[t]),
                    (__attribute__((address_space(3))) unsigned*)(&lds[bb + ldsoff[t]]),
                    16, 0, 0);
                gp[t] += gstep[t];
            }
            __builtin_amdgcn_s_waitcnt(0x0F74);   // vmcnt(4)
        } else {
            __builtin_amdgcn_s_waitcnt(0x0F70);   // vmcnt(0)
        }
        asm volatile("" ::: "memory");
        __builtin_amdgcn_s_barrier();
        asm volatile("" ::: "memory");

        const unsigned short* buf = &lds[(it & 1) * 16384];

        FragU ahi[2], alo[2];
        #pragma unroll
        for (int i = 0; i < 2; ++i) {
            #pragma unroll
            for (int h = 0; h < 2; ++h) {
                float4 f = *(const float4*)(buf + aoff[i][h]);
                unsigned bx = __builtin_bit_cast(unsigned, f.x);
                unsigned by = __builtin_bit_cast(unsigned, f.y);
                unsigned bz = __builtin_bit_cast(unsigned, f.z);
                unsigned bw = __builtin_bit_cast(unsigned, f.w);
                ahi[i].u[h * 2]     = __builtin_amdgcn_perm(by, bx, 0x07060302);
                ahi[i].u[h * 2 + 1] = __builtin_amdgcn_perm(bw, bz, 0x07060302);
                float lx = f.x - __builtin_bit_cast(float, bx & 0xFFFF0000u);
                float ly = f.y - __builtin_bit_cast(float, by & 0xFFFF0000u);
                float lz = f.z - __builtin_bit_cast(float, bz & 0xFFFF0000u);
                float lw = f.w - __builtin_bit_cast(float, bw & 0xFFFF0000u);
                alo[i].u[h * 2]     = __builtin_amdgcn_perm(
                    __builtin_bit_cast(unsigned, ly), __builtin_bit_cast(unsigned, lx), 0x07060302);
                alo[i].u[h * 2 + 1] = __builtin_amdgcn_perm(
                    __builtin_bit_cast(unsigned, lw), __builtin_bit_cast(unsigned, lz), 0x07060302);
            }
        }
        FragU bhi[4], blo[4];
        #pragma unroll
        for (int j = 0; j < 4; ++j) {
            bhi[j].v = *(const bf16x8*)(buf +  8192 + boff[j]);
            blo[j].v = *(const bf16x8*)(buf + 12288 + boff[j]);
        }
        #pragma unroll
        for (int i = 0; i < 2; ++i)
            #pragma unroll
            for (int j = 0; j < 4; ++j) {
                acc[i][j] = __builtin_amdgcn_mfma_f32_16x16x32_bf16(ahi[i].v, bhi[j].v, acc[i][j], 0, 0, 0);
                acc[i][j] = __builtin_amdgcn_mfma_f32_16x16x32_bf16(alo[i].v, bhi[j].v, acc[i][j], 0, 0, 0);
                acc[i][j] = __builtin_amdgcn_mfma_f32_16x16x32_bf16(ahi[i].v, blo[j].v, acc[i][j], 0, 0, 0);
            }
    }

    #pragma unroll
    for (int i = 0; i < 2; ++i) {
        #pragma unroll
        for (int reg = 0; reg < 4; ++reg) {
            int mg = m0 + wm + i * 16 + q * 4 + reg;
            float* dst = Cc + (size_t)mg * N_ + n0 + wn + r;
            dst[0]  = acc[i][0][reg];
            dst[16] = acc[i][1][reg];
            dst[32] = acc[i][2][reg];
            dst[48] = acc[i][3][reg];
        }
    }
}

// ---------------------------------------------------------------------------
// GEMM2: all operands pre-split bf16 planes (A = x planes from scan_apply).
// Same schedule as GEMM1, no fp32 split. No XCD swizzle (see GEMM1 note).
// ---------------------------------------------------------------------------
__global__ __launch_bounds__(512, 4) void gemm_presplit(
    const unsigned short* __restrict__ Athi, const unsigned short* __restrict__ Atlo,
    const unsigned short* __restrict__ Bthi, const unsigned short* __restrict__ Btlo,
    float* __restrict__ Cc, int N_, int K)
{
    __shared__ unsigned short lds[2 * 16384];   // 64 KB

    const int tid  = threadIdx.x;
    const int wave = tid >> 6;
    const int lane = tid & 63;
    const int n0 = blockIdx.x * 128;
    const int m0 = blockIdx.y * 128;

    const char* gp[4];
    int ldsoff[4];
    #pragma unroll
    for (int t = 0; t < 4; ++t) {
        int gi = wave * 4 + t;
        int plane = gi >> 3;                // 0=Ahi 1=Alo 2=Bhi 3=Blo
        int pi = gi & 7;
        int p = pi * 64 + lane;
        int row = p >> 2, s = p & 3;
        int l = s ^ ((row >> 1) & 3);
        const unsigned short* base =
            (plane == 0) ? Athi : (plane == 1) ? Atlo : (plane == 2) ? Bthi : Btlo;
        int r0 = (plane < 2) ? m0 : n0;
        gp[t] = (const char*)(base + (size_t)(r0 + row) * K + l * 8);
        ldsoff[t] = plane * 4096 + pi * 512;
    }

    const int r = lane & 15, q = lane >> 4;
    const int wm = (wave >> 2) * 64, wn = (wave & 3) * 32;

    int aoff[4], boff[2];
    #pragma unroll
    for (int i = 0; i < 4; ++i) {
        int row = wm + i * 16 + r;
        aoff[i] = row * 32 + (q ^ ((row >> 1) & 3)) * 8;
    }
    #pragma unroll
    for (int j = 0; j < 2; ++j) {
        int row = wn + j * 16 + r;
        boff[j] = row * 32 + (q ^ ((row >> 1) & 3)) * 8;
    }

    f32x4 acc[4][2];
    #pragma unroll
    for (int i = 0; i < 4; ++i)
        #pragma unroll
        for (int j = 0; j < 2; ++j)
            acc[i][j] = (f32x4){0.f, 0.f, 0.f, 0.f};

    #pragma unroll
    for (int t = 0; t < 4; ++t) {
        __builtin_amdgcn_global_load_lds(
            (const __attribute__((address_space(1))) unsigned*)(gp[t]),
            (__attribute__((address_space(3))) unsigned*)(&lds[ldsoff[t]]),
            16, 0, 0);
        gp[t] += 64;                        // BK bf16 = 64 B
    }

    const int nit = K >> 5;
    for (int it = 0; it < nit; ++it) {
        asm volatile("" ::: "memory");
        __builtin_amdgcn_s_barrier();
        asm volatile("" ::: "memory");
        if (it + 1 < nit) {
            const int bb = ((it + 1) & 1) * 16384;
            #pragma unroll
            for (int t = 0; t < 4; ++t) {
                __builtin_amdgcn_global_load_lds(
                    (const __attribute__((address_space(1))) unsigned*)(gp[t]),
                    (__attribute__((address_space(3))) unsigned*)(&lds[bb + ldsoff[t]]),
                    16, 0, 0);
                gp[t] += 64;
            }
            __builtin_amdgcn_s_waitcnt(0x0F74);   // vmcnt(4)
        } else {
            __builtin_amdgcn_s_waitcnt(0x0F70);   // vmcnt(0)
        }
        asm volatile("" ::: "memory");
        __builtin_amdgcn_s_barrier();
        asm volatile("" ::: "memory");

        const unsigned short* buf = &lds[(it & 1) * 16384];

        FragU ahi[4], alo[4];
        #pragma unroll
        for (int i = 0; i < 4; ++i) {
            ahi[i].v = *(const bf16x8*)(buf +        aoff[i]);
            alo[i].v = *(const bf16x8*)(buf + 4096 + aoff[i]);
        }
        FragU bhi[2], blo[2];
        #pragma unroll
        for (int j = 0; j < 2; ++j) {
            bhi[j].v = *(const bf16x8*)(buf +  8192 + boff[j]);
            blo[j].v = *(const bf16x8*)(buf + 12288 + boff[j]);
        }
        #pragma unroll
        for (int i = 0; i < 4; ++i)
            #pragma unroll
            for (int j = 0; j < 2; ++j) {
                acc[i][j] = __builtin_amdgcn_mfma_f32_16x16x32_bf16(ahi[i].v, bhi[j].v, acc[i][j], 0, 0, 0);
                acc[i][j] = __builtin_amdgcn_mfma_f32_16x16x32_bf16(alo[i].v, bhi[j].v, acc[i][j], 0, 0, 0);
                acc[i][j] = __builtin_amdgcn_mfma_f32_16x16x32_bf16(ahi[i].v, blo[j].v, acc[i][j], 0, 0, 0);
            }
    }

    #pragma unroll
    for (int i = 0; i < 4; ++i) {
        #pragma unroll
        for (int reg = 0; reg < 4; ++reg) {
            int mg = m0 + wm + i * 16 + q * 4 + reg;
            float* dst = Cc + (size_t)mg * N_ + n0 + wn + r;
            dst[0]  = acc[i][0][reg];
            dst[16] = acc[i][1][reg];
        }
    }
}

// ---------------------------------------------------------------------------
// Scan phase A: per-chunk carry, LC=16, one wave per (b,chunk), float4/thread.
// ---------------------------------------------------------------------------
__global__ __launch_bounds__(64) void scan_carry(
    const float* __restrict__ uB, const float* __restrict__ A,
    float* __restrict__ carry)
{
    const int b = blockIdx.x;
    const int c = blockIdx.y;
    const int t = threadIdx.x;              // states n = 4t..4t+3
    const float4 a = *(const float4*)(A + 4 * t);
    const float4* p = (const float4*)(uB + ((size_t)b * LENGTH + (size_t)c * LC) * STATE) + t;
    float4 s = make_float4(0.f, 0.f, 0.f, 0.f);
    #pragma unroll
    for (int j = 0; j < LC; ++j) {
        float4 v = p[(size_t)j * (STATE / 4)];
        s.x = fmaf(a.x, s.x, v.x);
        s.y = fmaf(a.y, s.y, v.y);
        s.z = fmaf(a.z, s.z, v.z);
        s.w = fmaf(a.w, s.w, v.w);
    }
    *((float4*)(carry + ((size_t)b * NC + c) * STATE) + t) = s;
}

// ---------------------------------------------------------------------------
// Scan phase B: entry-state scan over chunks. One 256-thread block per batch
// (n = tid). 256 serial steps: entry[c] = s; s = a^LC * s + carry[c].
// Unroll x8 so the (chain-independent) carry loads pipeline; fully coalesced
// 1KB rows. Traffic 4 MB total -> a few us. Kills apply's O(NC) rebuild.
// ---------------------------------------------------------------------------
__global__ __launch_bounds__(256) void scan_entries(
    const float* __restrict__ carry, const float* __restrict__ A,
    const float* __restrict__ x0, float* __restrict__ entry)
{
    const int b = blockIdx.x;
    const int n = threadIdx.x;
    const float a = A[n];
    float aL = a;
    #pragma unroll
    for (int k = 0; k < 4; ++k) aL *= aL;   // a^16 = a^LC

    float s = x0[(size_t)b * STATE + n];
    const float* cr = carry + (size_t)b * NC * STATE + n;
    float* en = entry + (size_t)b * NC * STATE + n;
    #pragma unroll 8
    for (int c = 0; c < NC; ++c) {
        en[(size_t)c * STATE] = s;
        s = fmaf(aL, s, cr[(size_t)c * STATE]);
    }
}

// ---------------------------------------------------------------------------
// Scan phase C (apply): entry state is a single 1KB load (no rebuild loop),
// then 16 streaming steps writing x as trunc-split hi/lo bf16 planes.
// Pure BW kernel: 2048 one-wave blocks, ~64 MB traffic.
// ---------------------------------------------------------------------------
__global__ __launch_bounds__(64) void scan_apply(
    const float* __restrict__ uB, const float* __restrict__ A,
    const float* __restrict__ entry,
    unsigned short* __restrict__ xhi, unsigned short* __restrict__ xlo,
    float* __restrict__ x_last)
{
    const int b = blockIdx.x;
    const int c = blockIdx.y;
    const int t = threadIdx.x;              // states n = 4t..4t+3
    const float4 a = *(const float4*)(A + 4 * t);

    float4 s = *((const float4*)(entry + ((size_t)b * NC + c) * STATE) + t);

    const size_t base = ((size_t)b * LENGTH + (size_t)c * LC) * STATE;
    const float4* p = (const float4*)(uB + base) + t;
    u16x4* qh = (u16x4*)(xhi + base) + t;
    u16x4* ql = (u16x4*)(xlo + base) + t;
    #pragma unroll
    for (int j = 0; j < LC; ++j) {
        float4 v = p[(size_t)j * (STATE / 4)];
        s.x = fmaf(a.x, s.x, v.x);
        s.y = fmaf(a.y, s.y, v.y);
        s.z = fmaf(a.z, s.z, v.z);
        s.w = fmaf(a.w, s.w, v.w);
        u16x4 hh, ll;
        unsigned ux = __builtin_bit_cast(unsigned, s.x);
        unsigned uy = __builtin_bit_cast(unsigned, s.y);
        unsigned uz = __builtin_bit_cast(unsigned, s.z);
        unsigned uw = __builtin_bit_cast(unsigned, s.w);
        hh[0] = (unsigned short)(ux >> 16);
        hh[1] = (unsigned short)(uy >> 16);
        hh[2] = (unsigned short)(uz >> 16);
        hh[3] = (unsigned short)(uw >> 16);
        float lx = s.x - __builtin_bit_cast(float, ux & 0xFFFF0000u);
        float ly = s.y - __builtin_bit_cast(float, uy & 0xFFFF0000u);
        float lz = s.z - __builtin_bit_cast(float, uz & 0xFFFF0000u);
        float lw = s.w - __builtin_bit_cast(float, uw & 0xFFFF0000u);
        ll[0] = (unsigned short)(__builtin_bit_cast(unsigned, lx) >> 16);
        ll[1] = (unsigned short)(__builtin_bit_cast(unsigned, ly) >> 16);
        ll[2] = (unsigned short)(__builtin_bit_cast(unsigned, lz) >> 16);
        ll[3] = (unsigned short)(__builtin_bit_cast(unsigned, lw) >> 16);
        qh[(size_t)j * (STATE / 4)] = hh;
        ql[(size_t)j * (STATE / 4)] = ll;
    }
    if (c == NC - 1)
        *((float4*)(x_last + (size_t)b * STATE) + t) = s;
}

// ---------------------------------------------------------------------------
extern "C" void kernel_launch(void* const* d_in, const int* in_sizes, int n_in,
                              void* d_out, int out_size, void* d_ws, size_t ws_size,
                              hipStream_t stream)
{
    const float* u  = (const float*)d_in[0];   // [8,4096,512]
    const float* x0 = (const float*)d_in[1];   // [8,256]
    const float* A  = (const float*)d_in[2];   // [256]
    const float* B  = (const float*)d_in[3];   // [512,256]
    const float* C  = (const float*)d_in[4];   // [256,512]

    const size_t MB = 1024 * 1024;
    char* ws = (char*)d_ws;

    unsigned short* xhi = (unsigned short*)(ws);                // [M,256] bf16, 16 MB
    unsigned short* xlo = (unsigned short*)(ws + 16 * MB);      // [M,256] bf16, 16 MB
    float* carry = (float*)(ws + 32 * MB);                      // [8,256,256] fp32, 2 MB
    float* entry = (float*)(ws + 34 * MB);                      // [8,256,256] fp32, 2 MB
    unsigned short* Bt_hi = (unsigned short*)(ws + 36 * MB);                // 256 KB
    unsigned short* Bt_lo = (unsigned short*)(ws + 36 * MB + 256 * 1024);   // 256 KB
    unsigned short* Ct_hi = (unsigned short*)(ws + 36 * MB + 512 * 1024);   // 256 KB
    unsigned short* Ct_lo = (unsigned short*)(ws + 36 * MB + 768 * 1024);   // 256 KB

    float* y      = (float*)d_out;                             // [8,4096,512] = 64 MB
    float* x_last = y + (size_t)BATCH * LENGTH * OUT_DIM;      // [8,256]
    // uB parks in the upper half of y's region; dead before GEMM2 writes y.
    float* uB     = (float*)((char*)d_out + 32 * MB);          // [M,256] = 32 MB

    const int M = BATCH * LENGTH;   // 32768

    // 1. split+transpose both weights to bf16 hi/lo planes
    split_weights<<<dim3((IN_DIM * STATE + STATE * OUT_DIM) / 256), dim3(256), 0, stream>>>(
        B, C, Bt_hi, Bt_lo, Ct_hi, Ct_lo);

    // 2. GEMM1: uB[M,256] = u[M,512] @ B
    gemm_dbuf<<<dim3(STATE / 128, M / 128), dim3(512), 0, stream>>>(
        u, Bt_hi, Bt_lo, uB, STATE, IN_DIM);

    // 3. three-phase scan (fp32 exact): carries -> entry states -> apply
    scan_carry<<<dim3(BATCH, NC), dim3(64), 0, stream>>>(uB, A, carry);
    scan_entries<<<dim3(BATCH), dim3(256), 0, stream>>>(carry, A, x0, entry);
    scan_apply<<<dim3(BATCH, NC), dim3(64), 0, stream>>>(uB, A, entry, xhi, xlo, x_last);

    // 4. GEMM2: y[M,512] = x[M,256] @ C  (all operands pre-split bf16)
    gemm_presplit<<<dim3(OUT_DIM / 128, M / 128), dim3(512), 0, stream>>>(
        xhi, xlo, Ct_hi, Ct_lo, y, OUT_DIM, STATE);
}

// Round 4
// 205.787 us; speedup vs baseline: 1.1606x; 1.0141x over previous
//
#include <hip/hip_runtime.h>

#define BATCH   8
#define LENGTH  4096
#define IN_DIM  512
#define STATE   256
#define OUT_DIM 512
#define NC      256
#define LC      16

typedef __attribute__((ext_vector_type(8))) short bf16x8;
typedef __attribute__((ext_vector_type(4))) float f32x4;
typedef __attribute__((ext_vector_type(4))) unsigned short u16x4;

union FragU { bf16x8 v; unsigned u[4]; };

__device__ __forceinline__ unsigned short bf16_rne(float v) {
    unsigned u = __builtin_bit_cast(unsigned, v);
    unsigned r = (u + 0x7FFFu + ((u >> 16) & 1u)) >> 16;
    return (unsigned short)r;
}
__device__ __forceinline__ float bf16_f(unsigned short h) {
    unsigned u = ((unsigned)h) << 16;
    return __builtin_bit_cast(float, u);
}

// ---------------------------------------------------------------------------
// Merged weight split+transpose: B[512][256] and C[256][512] fp32 ->
// hi/lo bf16 planes [N][K] (RNE).
// ---------------------------------------------------------------------------
__global__ __launch_bounds__(256) void split_weights(
    const float* __restrict__ B, const float* __restrict__ C,
    unsigned short* __restrict__ Bhi, unsigned short* __restrict__ Blo,
    unsigned short* __restrict__ Chi, unsigned short* __restrict__ Clo)
{
    int id = blockIdx.x * 256 + threadIdx.x;
    if (id < IN_DIM * STATE) {
        int k = id & (IN_DIM - 1), n = id >> 9;      // Bt[n=state][k=in]
        float v = B[(size_t)k * STATE + n];
        unsigned short h = bf16_rne(v);
        Bhi[id] = h;
        Blo[id] = bf16_rne(v - bf16_f(h));
    } else {
        int id2 = id - IN_DIM * STATE;
        int k = id2 & (STATE - 1), n = id2 >> 8;     // Ct[n=out][k=state]
        float v = C[(size_t)k * OUT_DIM + n];
        unsigned short h = bf16_rne(v);
        Chi[id2] = h;
        Clo[id2] = bf16_rne(v - bf16_f(h));
    }
}

// ---------------------------------------------------------------------------
// GEMM1 + fused scan phase A.
// Split-bf16 MFMA GEMM, A read as fp32 (in-register hi/lo split).
// Tile 128x128, BK=32, 8 waves (4Mx2N), LDS 2x32KB double buffer,
// raw s_barrier + vmcnt(4) counted prefetch.
// Epilogue additionally emits carry[b][chunk][n] = sum_{j<16} a^(15-j)*uB[j][n]:
// fragment i's rows (q*4+reg) are exactly one 16-row chunk, so the chunk
// reduction is 4 weighted in-lane FMAs + shfl_xor(16)+shfl_xor(32) over q.
// Kills the separate scan_carry kernel (one dispatch + 32 MB read).
// ---------------------------------------------------------------------------
__global__ __launch_bounds__(512, 4) void gemm_dbuf(
    const float* __restrict__ Af, const unsigned short* __restrict__ Bthi,
    const unsigned short* __restrict__ Btlo, float* __restrict__ Cc,
    const float* __restrict__ Av, float* __restrict__ carry,
    int N_, int K)
{
    __shared__ unsigned short lds[2 * 16384];   // 64 KB

    const int tid  = threadIdx.x;
    const int wave = tid >> 6;
    const int lane = tid & 63;
    const int n0 = blockIdx.x * 128;
    const int m0 = blockIdx.y * 128;

    // --- staging descriptors: 32 wave-instructions of 1KB; 4 per wave ---
    const char* gp[4];
    int ldsoff[4], gstep[4];
    #pragma unroll
    for (int t = 0; t < 4; ++t) {
        int gi = wave * 4 + t;
        if (gi < 16) {          // A plane: 1024 slots (16 KB)
            int p = gi * 64 + lane;
            int row = p >> 3, s = p & 7;
            int l = s ^ (row & 7);
            gp[t] = (const char*)(Af + (size_t)(m0 + row) * K + l * 4);
            gstep[t] = 32 * 4;              // BK fp32
            ldsoff[t] = gi * 512;
        } else {                // B planes: 512 slots each (8 KB)
            int q2 = (gi - 16) >> 3;        // 0 = hi, 1 = lo
            int pi = gi & 7;
            int p = pi * 64 + lane;
            int row = p >> 2, s = p & 3;
            int l = s ^ ((row >> 1) & 3);
            const unsigned short* base = q2 ? Btlo : Bthi;
            gp[t] = (const char*)(base + (size_t)(n0 + row) * K + l * 8);
            gstep[t] = 32 * 2;              // BK bf16
            ldsoff[t] = 8192 + q2 * 4096 + pi * 512;
        }
    }

    const int r = lane & 15, q = lane >> 4;
    const int wm = (wave >> 1) * 32, wn = (wave & 1) * 64;

    int aoff[2][2], boff[4];
    #pragma unroll
    for (int i = 0; i < 2; ++i) {
        int row = wm + i * 16 + r;
        #pragma unroll
        for (int h = 0; h < 2; ++h)
            aoff[i][h] = row * 64 + ((2 * q + h) ^ (row & 7)) * 8;
    }
    #pragma unroll
    for (int j = 0; j < 4; ++j) {
        int row = wn + j * 16 + r;
        boff[j] = row * 32 + (q ^ ((row >> 1) & 3)) * 8;
    }

    f32x4 acc[2][4];
    #pragma unroll
    for (int i = 0; i < 2; ++i)
        #pragma unroll
        for (int j = 0; j < 4; ++j)
            acc[i][j] = (f32x4){0.f, 0.f, 0.f, 0.f};

    #pragma unroll
    for (int t = 0; t < 4; ++t) {
        __builtin_amdgcn_global_load_lds(
            (const __attribute__((address_space(1))) unsigned*)(gp[t]),
            (__attribute__((address_space(3))) unsigned*)(&lds[ldsoff[t]]),
            16, 0, 0);
        gp[t] += gstep[t];
    }

    const int nit = K >> 5;
    for (int it = 0; it < nit; ++it) {
        asm volatile("" ::: "memory");
        __builtin_amdgcn_s_barrier();
        asm volatile("" ::: "memory");
        if (it + 1 < nit) {
            const int bb = ((it + 1) & 1) * 16384;
            #pragma unroll
            for (int t = 0; t < 4; ++t) {
                __builtin_amdgcn_global_load_lds(
                    (const __attribute__((address_space(1))) unsigned*)(gp[t]),
                    (__attribute__((address_space(3))) unsigned*)(&lds[bb + ldsoff[t]]),
                    16, 0, 0);
                gp[t] += gstep[t];
            }
            __builtin_amdgcn_s_waitcnt(0x0F74);   // vmcnt(4)
        } else {
            __builtin_amdgcn_s_waitcnt(0x0F70);   // vmcnt(0)
        }
        asm volatile("" ::: "memory");
        __builtin_amdgcn_s_barrier();
        asm volatile("" ::: "memory");

        const unsigned short* buf = &lds[(it & 1) * 16384];

        FragU ahi[2], alo[2];
        #pragma unroll
        for (int i = 0; i < 2; ++i) {
            #pragma unroll
            for (int h = 0; h < 2; ++h) {
                float4 f = *(const float4*)(buf + aoff[i][h]);
                unsigned bx = __builtin_bit_cast(unsigned, f.x);
                unsigned by = __builtin_bit_cast(unsigned, f.y);
                unsigned bz = __builtin_bit_cast(unsigned, f.z);
                unsigned bw = __builtin_bit_cast(unsigned, f.w);
                ahi[i].u[h * 2]     = __builtin_amdgcn_perm(by, bx, 0x07060302);
                ahi[i].u[h * 2 + 1] = __builtin_amdgcn_perm(bw, bz, 0x07060302);
                float lx = f.x - __builtin_bit_cast(float, bx & 0xFFFF0000u);
                float ly = f.y - __builtin_bit_cast(float, by & 0xFFFF0000u);
                float lz = f.z - __builtin_bit_cast(float, bz & 0xFFFF0000u);
                float lw = f.w - __builtin_bit_cast(float, bw & 0xFFFF0000u);
                alo[i].u[h * 2]     = __builtin_amdgcn_perm(
                    __builtin_bit_cast(unsigned, ly), __builtin_bit_cast(unsigned, lx), 0x07060302);
                alo[i].u[h * 2 + 1] = __builtin_amdgcn_perm(
                    __builtin_bit_cast(unsigned, lw), __builtin_bit_cast(unsigned, lz), 0x07060302);
            }
        }
        FragU bhi[4], blo[4];
        #pragma unroll
        for (int j = 0; j < 4; ++j) {
            bhi[j].v = *(const bf16x8*)(buf +  8192 + boff[j]);
            blo[j].v = *(const bf16x8*)(buf + 12288 + boff[j]);
        }
        #pragma unroll
        for (int i = 0; i < 2; ++i)
            #pragma unroll
            for (int j = 0; j < 4; ++j) {
                acc[i][j] = __builtin_amdgcn_mfma_f32_16x16x32_bf16(ahi[i].v, bhi[j].v, acc[i][j], 0, 0, 0);
                acc[i][j] = __builtin_amdgcn_mfma_f32_16x16x32_bf16(alo[i].v, bhi[j].v, acc[i][j], 0, 0, 0);
                acc[i][j] = __builtin_amdgcn_mfma_f32_16x16x32_bf16(ahi[i].v, blo[j].v, acc[i][j], 0, 0, 0);
            }
    }

    // epilogue: C/D layout col = lane&15, row = q*4 + reg
    #pragma unroll
    for (int i = 0; i < 2; ++i) {
        #pragma unroll
        for (int reg = 0; reg < 4; ++reg) {
            int mg = m0 + wm + i * 16 + q * 4 + reg;
            float* dst = Cc + (size_t)mg * N_ + n0 + wn + r;
            dst[0]  = acc[i][0][reg];
            dst[16] = acc[i][1][reg];
            dst[32] = acc[i][2][reg];
            dst[48] = acc[i][3][reg];
        }
    }

    // fused scan phase A: carry[b][c][n] = sum_{row=0..15} a_n^(15-row) uB[row][n]
    // row_in_chunk = q*4+reg -> weight = a^(12-4q) * a^(3-reg)
    {
        const int b  = m0 >> 12;                    // LENGTH = 4096
        const int c0 = ((m0 & 4095) + wm) >> 4;     // chunk of fragment i=0
        #pragma unroll
        for (int j = 0; j < 4; ++j) {
            const int n = n0 + wn + j * 16 + r;
            const float a  = Av[n];
            const float a2 = a * a, a3 = a2 * a, a4 = a2 * a2;
            const float a8 = a4 * a4, a12 = a8 * a4;
            const float base = (q == 0) ? a12 : (q == 1) ? a8 : (q == 2) ? a4 : 1.f;
            #pragma unroll
            for (int i = 0; i < 2; ++i) {
                float partial = base * (a3 * acc[i][j][0] + a2 * acc[i][j][1]
                                      + a  * acc[i][j][2] +      acc[i][j][3]);
                partial += __shfl_xor(partial, 16);
                partial += __shfl_xor(partial, 32);
                if (q == 0)
                    carry[((size_t)b * NC + (c0 + i)) * STATE + n] = partial;
            }
        }
    }
}

// ---------------------------------------------------------------------------
// GEMM2: all operands pre-split bf16 planes (A = x planes from scan_apply).
// Same schedule as GEMM1, no fp32 split. No XCD swizzle.
// ---------------------------------------------------------------------------
__global__ __launch_bounds__(512, 4) void gemm_presplit(
    const unsigned short* __restrict__ Athi, const unsigned short* __restrict__ Atlo,
    const unsigned short* __restrict__ Bthi, const unsigned short* __restrict__ Btlo,
    float* __restrict__ Cc, int N_, int K)
{
    __shared__ unsigned short lds[2 * 16384];   // 64 KB

    const int tid  = threadIdx.x;
    const int wave = tid >> 6;
    const int lane = tid & 63;
    const int n0 = blockIdx.x * 128;
    const int m0 = blockIdx.y * 128;

    const char* gp[4];
    int ldsoff[4];
    #pragma unroll
    for (int t = 0; t < 4; ++t) {
        int gi = wave * 4 + t;
        int plane = gi >> 3;                // 0=Ahi 1=Alo 2=Bhi 3=Blo
        int pi = gi & 7;
        int p = pi * 64 + lane;
        int row = p >> 2, s = p & 3;
        int l = s ^ ((row >> 1) & 3);
        const unsigned short* base =
            (plane == 0) ? Athi : (plane == 1) ? Atlo : (plane == 2) ? Bthi : Btlo;
        int r0 = (plane < 2) ? m0 : n0;
        gp[t] = (const char*)(base + (size_t)(r0 + row) * K + l * 8);
        ldsoff[t] = plane * 4096 + pi * 512;
    }

    const int r = lane & 15, q = lane >> 4;
    const int wm = (wave >> 2) * 64, wn = (wave & 3) * 32;

    int aoff[4], boff[2];
    #pragma unroll
    for (int i = 0; i < 4; ++i) {
        int row = wm + i * 16 + r;
        aoff[i] = row * 32 + (q ^ ((row >> 1) & 3)) * 8;
    }
    #pragma unroll
    for (int j = 0; j < 2; ++j) {
        int row = wn + j * 16 + r;
        boff[j] = row * 32 + (q ^ ((row >> 1) & 3)) * 8;
    }

    f32x4 acc[4][2];
    #pragma unroll
    for (int i = 0; i < 4; ++i)
        #pragma unroll
        for (int j = 0; j < 2; ++j)
            acc[i][j] = (f32x4){0.f, 0.f, 0.f, 0.f};

    #pragma unroll
    for (int t = 0; t < 4; ++t) {
        __builtin_amdgcn_global_load_lds(
            (const __attribute__((address_space(1))) unsigned*)(gp[t]),
            (__attribute__((address_space(3))) unsigned*)(&lds[ldsoff[t]]),
            16, 0, 0);
        gp[t] += 64;                        // BK bf16 = 64 B
    }

    const int nit = K >> 5;
    for (int it = 0; it < nit; ++it) {
        asm volatile("" ::: "memory");
        __builtin_amdgcn_s_barrier();
        asm volatile("" ::: "memory");
        if (it + 1 < nit) {
            const int bb = ((it + 1) & 1) * 16384;
            #pragma unroll
            for (int t = 0; t < 4; ++t) {
                __builtin_amdgcn_global_load_lds(
                    (const __attribute__((address_space(1))) unsigned*)(gp[t]),
                    (__attribute__((address_space(3))) unsigned*)(&lds[bb + ldsoff[t]]),
                    16, 0, 0);
                gp[t] += 64;
            }
            __builtin_amdgcn_s_waitcnt(0x0F74);   // vmcnt(4)
        } else {
            __builtin_amdgcn_s_waitcnt(0x0F70);   // vmcnt(0)
        }
        asm volatile("" ::: "memory");
        __builtin_amdgcn_s_barrier();
        asm volatile("" ::: "memory");

        const unsigned short* buf = &lds[(it & 1) * 16384];

        FragU ahi[4], alo[4];
        #pragma unroll
        for (int i = 0; i < 4; ++i) {
            ahi[i].v = *(const bf16x8*)(buf +        aoff[i]);
            alo[i].v = *(const bf16x8*)(buf + 4096 + aoff[i]);
        }
        FragU bhi[2], blo[2];
        #pragma unroll
        for (int j = 0; j < 2; ++j) {
            bhi[j].v = *(const bf16x8*)(buf +  8192 + boff[j]);
            blo[j].v = *(const bf16x8*)(buf + 12288 + boff[j]);
        }
        #pragma unroll
        for (int i = 0; i < 4; ++i)
            #pragma unroll
            for (int j = 0; j < 2; ++j) {
                acc[i][j] = __builtin_amdgcn_mfma_f32_16x16x32_bf16(ahi[i].v, bhi[j].v, acc[i][j], 0, 0, 0);
                acc[i][j] = __builtin_amdgcn_mfma_f32_16x16x32_bf16(alo[i].v, bhi[j].v, acc[i][j], 0, 0, 0);
                acc[i][j] = __builtin_amdgcn_mfma_f32_16x16x32_bf16(ahi[i].v, blo[j].v, acc[i][j], 0, 0, 0);
            }
    }

    #pragma unroll
    for (int i = 0; i < 4; ++i) {
        #pragma unroll
        for (int reg = 0; reg < 4; ++reg) {
            int mg = m0 + wm + i * 16 + q * 4 + reg;
            float* dst = Cc + (size_t)mg * N_ + n0 + wn + r;
            dst[0]  = acc[i][0][reg];
            dst[16] = acc[i][1][reg];
        }
    }
}

// ---------------------------------------------------------------------------
// Scan phase B: entry-state scan over chunks. One 256-thread block per batch
// (n = tid). 256 serial steps: entry[c] = s; s = a^LC * s + carry[c].
// ---------------------------------------------------------------------------
__global__ __launch_bounds__(256) void scan_entries(
    const float* __restrict__ carry, const float* __restrict__ A,
    const float* __restrict__ x0, float* __restrict__ entry)
{
    const int b = blockIdx.x;
    const int n = threadIdx.x;
    const float a = A[n];
    float aL = a;
    #pragma unroll
    for (int k = 0; k < 4; ++k) aL *= aL;   // a^16 = a^LC

    float s = x0[(size_t)b * STATE + n];
    const float* cr = carry + (size_t)b * NC * STATE + n;
    float* en = entry + (size_t)b * NC * STATE + n;
    #pragma unroll 8
    for (int c = 0; c < NC; ++c) {
        en[(size_t)c * STATE] = s;
        s = fmaf(aL, s, cr[(size_t)c * STATE]);
    }
}

// ---------------------------------------------------------------------------
// Scan phase C (apply): entry state is a single 1KB load; all 16 uB rows
// preloaded into registers (one vmcnt wait per block, not a serialized
// load-use chain), then 16 fma+split+store steps.
// ---------------------------------------------------------------------------
__global__ __launch_bounds__(64) void scan_apply(
    const float* __restrict__ uB, const float* __restrict__ A,
    const float* __restrict__ entry,
    unsigned short* __restrict__ xhi, unsigned short* __restrict__ xlo,
    float* __restrict__ x_last)
{
    const int b = blockIdx.x;
    const int c = blockIdx.y;
    const int t = threadIdx.x;              // states n = 4t..4t+3
    const float4 a = *(const float4*)(A + 4 * t);

    const size_t base = ((size_t)b * LENGTH + (size_t)c * LC) * STATE;
    const float4* p = (const float4*)(uB + base) + t;

    float4 v[LC];
    #pragma unroll
    for (int j = 0; j < LC; ++j) v[j] = p[(size_t)j * (STATE / 4)];

    float4 s = *((const float4*)(entry + ((size_t)b * NC + c) * STATE) + t);

    u16x4* qh = (u16x4*)(xhi + base) + t;
    u16x4* ql = (u16x4*)(xlo + base) + t;
    #pragma unroll
    for (int j = 0; j < LC; ++j) {
        s.x = fmaf(a.x, s.x, v[j].x);
        s.y = fmaf(a.y, s.y, v[j].y);
        s.z = fmaf(a.z, s.z, v[j].z);
        s.w = fmaf(a.w, s.w, v[j].w);
        u16x4 hh, ll;
        unsigned ux = __builtin_bit_cast(unsigned, s.x);
        unsigned uy = __builtin_bit_cast(unsigned, s.y);
        unsigned uz = __builtin_bit_cast(unsigned, s.z);
        unsigned uw = __builtin_bit_cast(unsigned, s.w);
        hh[0] = (unsigned short)(ux >> 16);
        hh[1] = (unsigned short)(uy >> 16);
        hh[2] = (unsigned short)(uz >> 16);
        hh[3] = (unsigned short)(uw >> 16);
        float lx = s.x - __builtin_bit_cast(float, ux & 0xFFFF0000u);
        float ly = s.y - __builtin_bit_cast(float, uy & 0xFFFF0000u);
        float lz = s.z - __builtin_bit_cast(float, uz & 0xFFFF0000u);
        float lw = s.w - __builtin_bit_cast(float, uw & 0xFFFF0000u);
        ll[0] = (unsigned short)(__builtin_bit_cast(unsigned, lx) >> 16);
        ll[1] = (unsigned short)(__builtin_bit_cast(unsigned, ly) >> 16);
        ll[2] = (unsigned short)(__builtin_bit_cast(unsigned, lz) >> 16);
        ll[3] = (unsigned short)(__builtin_bit_cast(unsigned, lw) >> 16);
        qh[(size_t)j * (STATE / 4)] = hh;
        ql[(size_t)j * (STATE / 4)] = ll;
    }
    if (c == NC - 1)
        *((float4*)(x_last + (size_t)b * STATE) + t) = s;
}

// ---------------------------------------------------------------------------
extern "C" void kernel_launch(void* const* d_in, const int* in_sizes, int n_in,
                              void* d_out, int out_size, void* d_ws, size_t ws_size,
                              hipStream_t stream)
{
    const float* u  = (const float*)d_in[0];   // [8,4096,512]
    const float* x0 = (const float*)d_in[1];   // [8,256]
    const float* A  = (const float*)d_in[2];   // [256]
    const float* B  = (const float*)d_in[3];   // [512,256]
    const float* C  = (const float*)d_in[4];   // [256,512]

    const size_t MB = 1024 * 1024;
    char* ws = (char*)d_ws;

    unsigned short* xhi = (unsigned short*)(ws);                // [M,256] bf16, 16 MB
    unsigned short* xlo = (unsigned short*)(ws + 16 * MB);      // [M,256] bf16, 16 MB
    float* carry = (float*)(ws + 32 * MB);                      // [8,256,256] fp32, 2 MB
    float* entry = (float*)(ws + 34 * MB);                      // [8,256,256] fp32, 2 MB
    unsigned short* Bt_hi = (unsigned short*)(ws + 36 * MB);                // 256 KB
    unsigned short* Bt_lo = (unsigned short*)(ws + 36 * MB + 256 * 1024);   // 256 KB
    unsigned short* Ct_hi = (unsigned short*)(ws + 36 * MB + 512 * 1024);   // 256 KB
    unsigned short* Ct_lo = (unsigned short*)(ws + 36 * MB + 768 * 1024);   // 256 KB

    float* y      = (float*)d_out;                             // [8,4096,512] = 64 MB
    float* x_last = y + (size_t)BATCH * LENGTH * OUT_DIM;      // [8,256]
    // uB parks in the upper half of y's region; dead before GEMM2 writes y.
    float* uB     = (float*)((char*)d_out + 32 * MB);          // [M,256] = 32 MB

    const int M = BATCH * LENGTH;   // 32768

    // 1. split+transpose both weights to bf16 hi/lo planes
    split_weights<<<dim3((IN_DIM * STATE + STATE * OUT_DIM) / 256), dim3(256), 0, stream>>>(
        B, C, Bt_hi, Bt_lo, Ct_hi, Ct_lo);

    // 2. GEMM1 (+fused scan phase A): uB = u @ B, carry per 16-row chunk
    gemm_dbuf<<<dim3(STATE / 128, M / 128), dim3(512), 0, stream>>>(
        u, Bt_hi, Bt_lo, uB, A, carry, STATE, IN_DIM);

    // 3. entry states + apply (fp32 exact)
    scan_entries<<<dim3(BATCH), dim3(256), 0, stream>>>(carry, A, x0, entry);
    scan_apply<<<dim3(BATCH, NC), dim3(64), 0, stream>>>(uB, A, entry, xhi, xlo, x_last);

    // 4. GEMM2: y[M,512] = x[M,256] @ C  (all operands pre-split bf16)
    gemm_presplit<<<dim3(OUT_DIM / 128, M / 128), dim3(512), 0, stream>>>(
        xhi, xlo, Ct_hi, Ct_lo, y, OUT_DIM, STATE);
}

// Round 5
// 194.649 us; speedup vs baseline: 1.2270x; 1.0572x over previous
//
#include <hip/hip_runtime.h>

#define BATCH   8
#define LENGTH  4096
#define IN_DIM  512
#define STATE   256
#define OUT_DIM 512
#define NC      256
#define LC      16

typedef __attribute__((ext_vector_type(8))) short bf16x8;
typedef __attribute__((ext_vector_type(4))) float f32x4;

union FragU { bf16x8 v; unsigned u[4]; };

__device__ __forceinline__ unsigned short bf16_rne(float v) {
    unsigned u = __builtin_bit_cast(unsigned, v);
    unsigned r = (u + 0x7FFFu + ((u >> 16) & 1u)) >> 16;
    return (unsigned short)r;
}
__device__ __forceinline__ float bf16_f(unsigned short h) {
    unsigned u = ((unsigned)h) << 16;
    return __builtin_bit_cast(float, u);
}

// ---------------------------------------------------------------------------
// Merged weight split+transpose: B[512][256] and C[256][512] fp32 ->
// hi/lo bf16 planes [N][K] (RNE).
// ---------------------------------------------------------------------------
__global__ __launch_bounds__(256) void split_weights(
    const float* __restrict__ B, const float* __restrict__ C,
    unsigned short* __restrict__ Bhi, unsigned short* __restrict__ Blo,
    unsigned short* __restrict__ Chi, unsigned short* __restrict__ Clo)
{
    int id = blockIdx.x * 256 + threadIdx.x;
    if (id < IN_DIM * STATE) {
        int k = id & (IN_DIM - 1), n = id >> 9;      // Bt[n=state][k=in]
        float v = B[(size_t)k * STATE + n];
        unsigned short h = bf16_rne(v);
        Bhi[id] = h;
        Blo[id] = bf16_rne(v - bf16_f(h));
    } else {
        int id2 = id - IN_DIM * STATE;
        int k = id2 & (STATE - 1), n = id2 >> 8;     // Ct[n=out][k=state]
        float v = C[(size_t)k * OUT_DIM + n];
        unsigned short h = bf16_rne(v);
        Chi[id2] = h;
        Clo[id2] = bf16_rne(v - bf16_f(h));
    }
}

// ---------------------------------------------------------------------------
// GEMM1 + fused scan phase A (unchanged from round 4).
// Tile 128x128, BK=32, 8 waves (4Mx2N), LDS 2x32KB dbuf, vmcnt(4) prefetch.
// Epilogue emits carry[b][chunk][n] = sum_{j<16} a^(15-j)*uB[j][n] via
// 4 weighted in-lane FMAs + shfl_xor(16/32).
// ---------------------------------------------------------------------------
__global__ __launch_bounds__(512, 4) void gemm_dbuf(
    const float* __restrict__ Af, const unsigned short* __restrict__ Bthi,
    const unsigned short* __restrict__ Btlo, float* __restrict__ Cc,
    const float* __restrict__ Av, float* __restrict__ carry,
    int N_, int K)
{
    __shared__ unsigned short lds[2 * 16384];   // 64 KB

    const int tid  = threadIdx.x;
    const int wave = tid >> 6;
    const int lane = tid & 63;
    const int n0 = blockIdx.x * 128;
    const int m0 = blockIdx.y * 128;

    const char* gp[4];
    int ldsoff[4], gstep[4];
    #pragma unroll
    for (int t = 0; t < 4; ++t) {
        int gi = wave * 4 + t;
        if (gi < 16) {          // A plane: 1024 slots (16 KB)
            int p = gi * 64 + lane;
            int row = p >> 3, s = p & 7;
            int l = s ^ (row & 7);
            gp[t] = (const char*)(Af + (size_t)(m0 + row) * K + l * 4);
            gstep[t] = 32 * 4;
            ldsoff[t] = gi * 512;
        } else {                // B planes: 512 slots each (8 KB)
            int q2 = (gi - 16) >> 3;
            int pi = gi & 7;
            int p = pi * 64 + lane;
            int row = p >> 2, s = p & 3;
            int l = s ^ ((row >> 1) & 3);
            const unsigned short* base = q2 ? Btlo : Bthi;
            gp[t] = (const char*)(base + (size_t)(n0 + row) * K + l * 8);
            gstep[t] = 32 * 2;
            ldsoff[t] = 8192 + q2 * 4096 + pi * 512;
        }
    }

    const int r = lane & 15, q = lane >> 4;
    const int wm = (wave >> 1) * 32, wn = (wave & 1) * 64;

    int aoff[2][2], boff[4];
    #pragma unroll
    for (int i = 0; i < 2; ++i) {
        int row = wm + i * 16 + r;
        #pragma unroll
        for (int h = 0; h < 2; ++h)
            aoff[i][h] = row * 64 + ((2 * q + h) ^ (row & 7)) * 8;
    }
    #pragma unroll
    for (int j = 0; j < 4; ++j) {
        int row = wn + j * 16 + r;
        boff[j] = row * 32 + (q ^ ((row >> 1) & 3)) * 8;
    }

    f32x4 acc[2][4];
    #pragma unroll
    for (int i = 0; i < 2; ++i)
        #pragma unroll
        for (int j = 0; j < 4; ++j)
            acc[i][j] = (f32x4){0.f, 0.f, 0.f, 0.f};

    #pragma unroll
    for (int t = 0; t < 4; ++t) {
        __builtin_amdgcn_global_load_lds(
            (const __attribute__((address_space(1))) unsigned*)(gp[t]),
            (__attribute__((address_space(3))) unsigned*)(&lds[ldsoff[t]]),
            16, 0, 0);
        gp[t] += gstep[t];
    }

    const int nit = K >> 5;
    for (int it = 0; it < nit; ++it) {
        asm volatile("" ::: "memory");
        __builtin_amdgcn_s_barrier();
        asm volatile("" ::: "memory");
        if (it + 1 < nit) {
            const int bb = ((it + 1) & 1) * 16384;
            #pragma unroll
            for (int t = 0; t < 4; ++t) {
                __builtin_amdgcn_global_load_lds(
                    (const __attribute__((address_space(1))) unsigned*)(gp[t]),
                    (__attribute__((address_space(3))) unsigned*)(&lds[bb + ldsoff[t]]),
                    16, 0, 0);
                gp[t] += gstep[t];
            }
            __builtin_amdgcn_s_waitcnt(0x0F74);   // vmcnt(4)
        } else {
            __builtin_amdgcn_s_waitcnt(0x0F70);   // vmcnt(0)
        }
        asm volatile("" ::: "memory");
        __builtin_amdgcn_s_barrier();
        asm volatile("" ::: "memory");

        const unsigned short* buf = &lds[(it & 1) * 16384];

        FragU ahi[2], alo[2];
        #pragma unroll
        for (int i = 0; i < 2; ++i) {
            #pragma unroll
            for (int h = 0; h < 2; ++h) {
                float4 f = *(const float4*)(buf + aoff[i][h]);
                unsigned bx = __builtin_bit_cast(unsigned, f.x);
                unsigned by = __builtin_bit_cast(unsigned, f.y);
                unsigned bz = __builtin_bit_cast(unsigned, f.z);
                unsigned bw = __builtin_bit_cast(unsigned, f.w);
                ahi[i].u[h * 2]     = __builtin_amdgcn_perm(by, bx, 0x07060302);
                ahi[i].u[h * 2 + 1] = __builtin_amdgcn_perm(bw, bz, 0x07060302);
                float lx = f.x - __builtin_bit_cast(float, bx & 0xFFFF0000u);
                float ly = f.y - __builtin_bit_cast(float, by & 0xFFFF0000u);
                float lz = f.z - __builtin_bit_cast(float, bz & 0xFFFF0000u);
                float lw = f.w - __builtin_bit_cast(float, bw & 0xFFFF0000u);
                alo[i].u[h * 2]     = __builtin_amdgcn_perm(
                    __builtin_bit_cast(unsigned, ly), __builtin_bit_cast(unsigned, lx), 0x07060302);
                alo[i].u[h * 2 + 1] = __builtin_amdgcn_perm(
                    __builtin_bit_cast(unsigned, lw), __builtin_bit_cast(unsigned, lz), 0x07060302);
            }
        }
        FragU bhi[4], blo[4];
        #pragma unroll
        for (int j = 0; j < 4; ++j) {
            bhi[j].v = *(const bf16x8*)(buf +  8192 + boff[j]);
            blo[j].v = *(const bf16x8*)(buf + 12288 + boff[j]);
        }
        #pragma unroll
        for (int i = 0; i < 2; ++i)
            #pragma unroll
            for (int j = 0; j < 4; ++j) {
                acc[i][j] = __builtin_amdgcn_mfma_f32_16x16x32_bf16(ahi[i].v, bhi[j].v, acc[i][j], 0, 0, 0);
                acc[i][j] = __builtin_amdgcn_mfma_f32_16x16x32_bf16(alo[i].v, bhi[j].v, acc[i][j], 0, 0, 0);
                acc[i][j] = __builtin_amdgcn_mfma_f32_16x16x32_bf16(ahi[i].v, blo[j].v, acc[i][j], 0, 0, 0);
            }
    }

    #pragma unroll
    for (int i = 0; i < 2; ++i) {
        #pragma unroll
        for (int reg = 0; reg < 4; ++reg) {
            int mg = m0 + wm + i * 16 + q * 4 + reg;
            float* dst = Cc + (size_t)mg * N_ + n0 + wn + r;
            dst[0]  = acc[i][0][reg];
            dst[16] = acc[i][1][reg];
            dst[32] = acc[i][2][reg];
            dst[48] = acc[i][3][reg];
        }
    }

    // fused scan phase A: carry[b][c][n] = sum_{row} a^(15-row) uB[row][n]
    {
        const int b  = m0 >> 12;
        const int c0 = ((m0 & 4095) + wm) >> 4;
        #pragma unroll
        for (int j = 0; j < 4; ++j) {
            const int n = n0 + wn + j * 16 + r;
            const float a  = Av[n];
            const float a2 = a * a, a3 = a2 * a, a4 = a2 * a2;
            const float a8 = a4 * a4, a12 = a8 * a4;
            const float base = (q == 0) ? a12 : (q == 1) ? a8 : (q == 2) ? a4 : 1.f;
            #pragma unroll
            for (int i = 0; i < 2; ++i) {
                float partial = base * (a3 * acc[i][j][0] + a2 * acc[i][j][1]
                                      + a  * acc[i][j][2] +      acc[i][j][3]);
                partial += __shfl_xor(partial, 16);
                partial += __shfl_xor(partial, 32);
                if (q == 0)
                    carry[((size_t)b * NC + (c0 + i)) * STATE + n] = partial;
            }
        }
    }
}

// ---------------------------------------------------------------------------
// Scan phase B: entry-state scan over chunks. One 256-thread block per batch.
// entry[c] = state BEFORE chunk c; final state = x_last. unroll 16 keeps 16
// independent carry loads in flight over the 256-step serial chain.
// ---------------------------------------------------------------------------
__global__ __launch_bounds__(256) void scan_entries(
    const float* __restrict__ carry, const float* __restrict__ A,
    const float* __restrict__ x0, float* __restrict__ entry,
    float* __restrict__ x_last)
{
    const int b = blockIdx.x;
    const int n = threadIdx.x;
    const float a = A[n];
    float aL = a;
    #pragma unroll
    for (int k = 0; k < 4; ++k) aL *= aL;   // a^16 = a^LC

    float s = x0[(size_t)b * STATE + n];
    const float* cr = carry + (size_t)b * NC * STATE + n;
    float* en = entry + (size_t)b * NC * STATE + n;
    #pragma unroll 16
    for (int c = 0; c < NC; ++c) {
        en[(size_t)c * STATE] = s;
        s = fmaf(aL, s, cr[(size_t)c * STATE]);
    }
    x_last[(size_t)b * STATE + n] = s;
}

// ---------------------------------------------------------------------------
// GEMM2 + fused scan phase C (apply): y[M,512] = scan(uB)[M,256] @ C.
// Stages the uB fp32 tile exactly like GEMM1 stages u (same swizzle, same
// 32KB/K-step, 64KB LDS dbuf, vmcnt(4)). After the staging barrier, threads
// 0..255 (one per (chunk,k): 8 chunks of 16 rows x 32 k) run the 16-step
// recurrence IN PLACE in LDS, seeded from entry[b][chunk][k]:
//   s = a_k*s + uB[row][k]; uB_lds[row][k] = s    (row = chunk*16 + j)
// Reads/writes are 4B over permuted full 128B rows -> 2-way banking (free).
// One lgkmcnt(0)+barrier later, the MFMA path consumes x via GEMM1's
// in-register fp32->hi/lo split. Bit-identical to scan_apply+presplit.
// ---------------------------------------------------------------------------
__global__ __launch_bounds__(512, 4) void gemm_scan_apply(
    const float* __restrict__ uB, const unsigned short* __restrict__ Bthi,
    const unsigned short* __restrict__ Btlo, const float* __restrict__ Av,
    const float* __restrict__ entry, float* __restrict__ Cc,
    int N_, int K)
{
    __shared__ unsigned short lds[2 * 16384];   // 64 KB

    const int tid  = threadIdx.x;
    const int wave = tid >> 6;
    const int lane = tid & 63;
    const int n0 = blockIdx.x * 128;
    const int m0 = blockIdx.y * 128;
    const int bb_ = m0 >> 12;               // batch
    const int c0_ = (m0 & 4095) >> 4;       // first chunk of this m-band

    const char* gp[4];
    int ldsoff[4], gstep[4];
    #pragma unroll
    for (int t = 0; t < 4; ++t) {
        int gi = wave * 4 + t;
        if (gi < 16) {          // uB fp32 plane: 16 KB
            int p = gi * 64 + lane;
            int row = p >> 3, s = p & 7;
            int l = s ^ (row & 7);
            gp[t] = (const char*)(uB + (size_t)(m0 + row) * K + l * 4);
            gstep[t] = 32 * 4;
            ldsoff[t] = gi * 512;
        } else {                // Ct hi/lo planes: 8 KB each
            int q2 = (gi - 16) >> 3;
            int pi = gi & 7;
            int p = pi * 64 + lane;
            int row = p >> 2, s = p & 3;
            int l = s ^ ((row >> 1) & 3);
            const unsigned short* base = q2 ? Btlo : Bthi;
            gp[t] = (const char*)(base + (size_t)(n0 + row) * K + l * 8);
            gstep[t] = 32 * 2;
            ldsoff[t] = 8192 + q2 * 4096 + pi * 512;
        }
    }

    const int r = lane & 15, q = lane >> 4;
    const int wm = (wave >> 1) * 32, wn = (wave & 1) * 64;

    int aoff[2][2], boff[4];
    #pragma unroll
    for (int i = 0; i < 2; ++i) {
        int row = wm + i * 16 + r;
        #pragma unroll
        for (int h = 0; h < 2; ++h)
            aoff[i][h] = row * 64 + ((2 * q + h) ^ (row & 7)) * 8;
    }
    #pragma unroll
    for (int j = 0; j < 4; ++j) {
        int row = wn + j * 16 + r;
        boff[j] = row * 32 + (q ^ ((row >> 1) & 3)) * 8;
    }

    // scan task: chunk sc (16 rows), state column sk (within BK)
    const int sc = tid >> 5;                // 0..15 (only <8 used)
    const int sk = tid & 31;

    f32x4 acc[2][4];
    #pragma unroll
    for (int i = 0; i < 2; ++i)
        #pragma unroll
        for (int j = 0; j < 4; ++j)
            acc[i][j] = (f32x4){0.f, 0.f, 0.f, 0.f};

    #pragma unroll
    for (int t = 0; t < 4; ++t) {
        __builtin_amdgcn_global_load_lds(
            (const __attribute__((address_space(1))) unsigned*)(gp[t]),
            (__attribute__((address_space(3))) unsigned*)(&lds[ldsoff[t]]),
            16, 0, 0);
        gp[t] += gstep[t];
    }

    const int nit = K >> 5;   // 8
    for (int it = 0; it < nit; ++it) {
        asm volatile("" ::: "memory");
        __builtin_amdgcn_s_barrier();
        asm volatile("" ::: "memory");
        if (it + 1 < nit) {
            const int bb = ((it + 1) & 1) * 16384;
            #pragma unroll
            for (int t = 0; t < 4; ++t) {
                __builtin_amdgcn_global_load_lds(
                    (const __attribute__((address_space(1))) unsigned*)(gp[t]),
                    (__attribute__((address_space(3))) unsigned*)(&lds[bb + ldsoff[t]]),
                    16, 0, 0);
                gp[t] += gstep[t];
            }
            __builtin_amdgcn_s_waitcnt(0x0F74);   // vmcnt(4)
        } else {
            __builtin_amdgcn_s_waitcnt(0x0F70);   // vmcnt(0)
        }
        asm volatile("" ::: "memory");
        __builtin_amdgcn_s_barrier();
        asm volatile("" ::: "memory");

        unsigned short* bufw = &lds[(it & 1) * 16384];
        const unsigned short* buf = bufw;

        // ---- fused scan phase C: uB tile -> x tile, in place (fp32) ----
        if (tid < 256) {
            const int kg = it * 32 + sk;
            const float a = Av[kg];
            float s = entry[((size_t)bb_ * NC + (c0_ + sc)) * STATE + kg];
            #pragma unroll
            for (int j = 0; j < 16; ++j) {
                int row = sc * 16 + j;
                int off = row * 64 + (((sk >> 2) ^ (row & 7)) * 8) + ((sk & 3) * 2);
                float v = *(const float*)(bufw + off);
                s = fmaf(a, s, v);
                *(float*)(bufw + off) = s;
            }
        }
        asm volatile("s_waitcnt lgkmcnt(0)" ::: "memory");
        __builtin_amdgcn_s_barrier();
        asm volatile("" ::: "memory");

        // ---- MFMA path: in-register fp32 -> hi/lo split on x ----
        FragU ahi[2], alo[2];
        #pragma unroll
        for (int i = 0; i < 2; ++i) {
            #pragma unroll
            for (int h = 0; h < 2; ++h) {
                float4 f = *(const float4*)(buf + aoff[i][h]);
                unsigned bx = __builtin_bit_cast(unsigned, f.x);
                unsigned by = __builtin_bit_cast(unsigned, f.y);
                unsigned bz = __builtin_bit_cast(unsigned, f.z);
                unsigned bw = __builtin_bit_cast(unsigned, f.w);
                ahi[i].u[h * 2]     = __builtin_amdgcn_perm(by, bx, 0x07060302);
                ahi[i].u[h * 2 + 1] = __builtin_amdgcn_perm(bw, bz, 0x07060302);
                float lx = f.x - __builtin_bit_cast(float, bx & 0xFFFF0000u);
                float ly = f.y - __builtin_bit_cast(float, by & 0xFFFF0000u);
                float lz = f.z - __builtin_bit_cast(float, bz & 0xFFFF0000u);
                float lw = f.w - __builtin_bit_cast(float, bw & 0xFFFF0000u);
                alo[i].u[h * 2]     = __builtin_amdgcn_perm(
                    __builtin_bit_cast(unsigned, ly), __builtin_bit_cast(unsigned, lx), 0x07060302);
                alo[i].u[h * 2 + 1] = __builtin_amdgcn_perm(
                    __builtin_bit_cast(unsigned, lw), __builtin_bit_cast(unsigned, lz), 0x07060302);
            }
        }
        FragU bhi[4], blo[4];
        #pragma unroll
        for (int j = 0; j < 4; ++j) {
            bhi[j].v = *(const bf16x8*)(buf +  8192 + boff[j]);
            blo[j].v = *(const bf16x8*)(buf + 12288 + boff[j]);
        }
        #pragma unroll
        for (int i = 0; i < 2; ++i)
            #pragma unroll
            for (int j = 0; j < 4; ++j) {
                acc[i][j] = __builtin_amdgcn_mfma_f32_16x16x32_bf16(ahi[i].v, bhi[j].v, acc[i][j], 0, 0, 0);
                acc[i][j] = __builtin_amdgcn_mfma_f32_16x16x32_bf16(alo[i].v, bhi[j].v, acc[i][j], 0, 0, 0);
                acc[i][j] = __builtin_amdgcn_mfma_f32_16x16x32_bf16(ahi[i].v, blo[j].v, acc[i][j], 0, 0, 0);
            }
    }

    #pragma unroll
    for (int i = 0; i < 2; ++i) {
        #pragma unroll
        for (int reg = 0; reg < 4; ++reg) {
            int mg = m0 + wm + i * 16 + q * 4 + reg;
            float* dst = Cc + (size_t)mg * N_ + n0 + wn + r;
            dst[0]  = acc[i][0][reg];
            dst[16] = acc[i][1][reg];
            dst[32] = acc[i][2][reg];
            dst[48] = acc[i][3][reg];
        }
    }
}

// ---------------------------------------------------------------------------
extern "C" void kernel_launch(void* const* d_in, const int* in_sizes, int n_in,
                              void* d_out, int out_size, void* d_ws, size_t ws_size,
                              hipStream_t stream)
{
    const float* u  = (const float*)d_in[0];   // [8,4096,512]
    const float* x0 = (const float*)d_in[1];   // [8,256]
    const float* A  = (const float*)d_in[2];   // [256]
    const float* B  = (const float*)d_in[3];   // [512,256]
    const float* C  = (const float*)d_in[4];   // [256,512]

    const size_t MB = 1024 * 1024;
    char* ws = (char*)d_ws;

    float* uB    = (float*)(ws);                // [M,256] fp32, 32 MB (outlives GEMM2 now)
    float* carry = (float*)(ws + 32 * MB);      // [8,256,256] fp32, 2 MB
    float* entry = (float*)(ws + 34 * MB);      // [8,256,256] fp32, 2 MB
    unsigned short* Bt_hi = (unsigned short*)(ws + 36 * MB);                // 256 KB
    unsigned short* Bt_lo = (unsigned short*)(ws + 36 * MB + 256 * 1024);   // 256 KB
    unsigned short* Ct_hi = (unsigned short*)(ws + 36 * MB + 512 * 1024);   // 256 KB
    unsigned short* Ct_lo = (unsigned short*)(ws + 36 * MB + 768 * 1024);   // 256 KB

    float* y      = (float*)d_out;                             // [8,4096,512] = 64 MB
    float* x_last = y + (size_t)BATCH * LENGTH * OUT_DIM;      // [8,256]

    const int M = BATCH * LENGTH;   // 32768

    // 1. split+transpose both weights to bf16 hi/lo planes
    split_weights<<<dim3((IN_DIM * STATE + STATE * OUT_DIM) / 256), dim3(256), 0, stream>>>(
        B, C, Bt_hi, Bt_lo, Ct_hi, Ct_lo);

    // 2. GEMM1 (+fused scan phase A): uB = u @ B, carry per 16-row chunk
    gemm_dbuf<<<dim3(STATE / 128, M / 128), dim3(512), 0, stream>>>(
        u, Bt_hi, Bt_lo, uB, A, carry, STATE, IN_DIM);

    // 3. entry states (+x_last)
    scan_entries<<<dim3(BATCH), dim3(256), 0, stream>>>(carry, A, x0, entry, x_last);

    // 4. GEMM2 (+fused scan phase C): y = scan(uB) @ C, x never materialized
    gemm_scan_apply<<<dim3(OUT_DIM / 128, M / 128), dim3(512), 0, stream>>>(
        uB, Ct_hi, Ct_lo, A, entry, y, OUT_DIM, STATE);
}

// Round 6
// 189.442 us; speedup vs baseline: 1.2607x; 1.0275x over previous
//
#include <hip/hip_runtime.h>

#define BATCH   8
#define LENGTH  4096
#define IN_DIM  512
#define STATE   256
#define OUT_DIM 512
#define NC      256
#define LC      16

typedef __attribute__((ext_vector_type(8))) short bf16x8;
typedef __attribute__((ext_vector_type(4))) float f32x4;

union FragU { bf16x8 v; unsigned u[4]; };

__device__ __forceinline__ unsigned short bf16_rne(float v) {
    unsigned u = __builtin_bit_cast(unsigned, v);
    unsigned r = (u + 0x7FFFu + ((u >> 16) & 1u)) >> 16;
    return (unsigned short)r;
}
__device__ __forceinline__ float bf16_f(unsigned short h) {
    unsigned u = ((unsigned)h) << 16;
    return __builtin_bit_cast(float, u);
}

// ---------------------------------------------------------------------------
// Merged weight split+transpose: B[512][256] and C[256][512] fp32 ->
// hi/lo bf16 planes [N][K] (RNE).
// ---------------------------------------------------------------------------
__global__ __launch_bounds__(256) void split_weights(
    const float* __restrict__ B, const float* __restrict__ C,
    unsigned short* __restrict__ Bhi, unsigned short* __restrict__ Blo,
    unsigned short* __restrict__ Chi, unsigned short* __restrict__ Clo)
{
    int id = blockIdx.x * 256 + threadIdx.x;
    if (id < IN_DIM * STATE) {
        int k = id & (IN_DIM - 1), n = id >> 9;      // Bt[n=state][k=in]
        float v = B[(size_t)k * STATE + n];
        unsigned short h = bf16_rne(v);
        Bhi[id] = h;
        Blo[id] = bf16_rne(v - bf16_f(h));
    } else {
        int id2 = id - IN_DIM * STATE;
        int k = id2 & (STATE - 1), n = id2 >> 8;     // Ct[n=out][k=state]
        float v = C[(size_t)k * OUT_DIM + n];
        unsigned short h = bf16_rne(v);
        Chi[id2] = h;
        Clo[id2] = bf16_rne(v - bf16_f(h));
    }
}

// ---------------------------------------------------------------------------
// GEMM1 + fused scan phase A (unchanged from round 5).
// ---------------------------------------------------------------------------
__global__ __launch_bounds__(512, 4) void gemm_dbuf(
    const float* __restrict__ Af, const unsigned short* __restrict__ Bthi,
    const unsigned short* __restrict__ Btlo, float* __restrict__ Cc,
    const float* __restrict__ Av, float* __restrict__ carry,
    int N_, int K)
{
    __shared__ unsigned short lds[2 * 16384];   // 64 KB

    const int tid  = threadIdx.x;
    const int wave = tid >> 6;
    const int lane = tid & 63;
    const int n0 = blockIdx.x * 128;
    const int m0 = blockIdx.y * 128;

    const char* gp[4];
    int ldsoff[4], gstep[4];
    #pragma unroll
    for (int t = 0; t < 4; ++t) {
        int gi = wave * 4 + t;
        if (gi < 16) {          // A plane: 1024 slots (16 KB)
            int p = gi * 64 + lane;
            int row = p >> 3, s = p & 7;
            int l = s ^ (row & 7);
            gp[t] = (const char*)(Af + (size_t)(m0 + row) * K + l * 4);
            gstep[t] = 32 * 4;
            ldsoff[t] = gi * 512;
        } else {                // B planes: 512 slots each (8 KB)
            int q2 = (gi - 16) >> 3;
            int pi = gi & 7;
            int p = pi * 64 + lane;
            int row = p >> 2, s = p & 3;
            int l = s ^ ((row >> 1) & 3);
            const unsigned short* base = q2 ? Btlo : Bthi;
            gp[t] = (const char*)(base + (size_t)(n0 + row) * K + l * 8);
            gstep[t] = 32 * 2;
            ldsoff[t] = 8192 + q2 * 4096 + pi * 512;
        }
    }

    const int r = lane & 15, q = lane >> 4;
    const int wm = (wave >> 1) * 32, wn = (wave & 1) * 64;

    int aoff[2][2], boff[4];
    #pragma unroll
    for (int i = 0; i < 2; ++i) {
        int row = wm + i * 16 + r;
        #pragma unroll
        for (int h = 0; h < 2; ++h)
            aoff[i][h] = row * 64 + ((2 * q + h) ^ (row & 7)) * 8;
    }
    #pragma unroll
    for (int j = 0; j < 4; ++j) {
        int row = wn + j * 16 + r;
        boff[j] = row * 32 + (q ^ ((row >> 1) & 3)) * 8;
    }

    f32x4 acc[2][4];
    #pragma unroll
    for (int i = 0; i < 2; ++i)
        #pragma unroll
        for (int j = 0; j < 4; ++j)
            acc[i][j] = (f32x4){0.f, 0.f, 0.f, 0.f};

    #pragma unroll
    for (int t = 0; t < 4; ++t) {
        __builtin_amdgcn_global_load_lds(
            (const __attribute__((address_space(1))) unsigned*)(gp[t]),
            (__attribute__((address_space(3))) unsigned*)(&lds[ldsoff[t]]),
            16, 0, 0);
        gp[t] += gstep[t];
    }

    const int nit = K >> 5;
    for (int it = 0; it < nit; ++it) {
        asm volatile("" ::: "memory");
        __builtin_amdgcn_s_barrier();
        asm volatile("" ::: "memory");
        if (it + 1 < nit) {
            const int bb = ((it + 1) & 1) * 16384;
            #pragma unroll
            for (int t = 0; t < 4; ++t) {
                __builtin_amdgcn_global_load_lds(
                    (const __attribute__((address_space(1))) unsigned*)(gp[t]),
                    (__attribute__((address_space(3))) unsigned*)(&lds[bb + ldsoff[t]]),
                    16, 0, 0);
                gp[t] += gstep[t];
            }
            __builtin_amdgcn_s_waitcnt(0x0F74);   // vmcnt(4)
        } else {
            __builtin_amdgcn_s_waitcnt(0x0F70);   // vmcnt(0)
        }
        asm volatile("" ::: "memory");
        __builtin_amdgcn_s_barrier();
        asm volatile("" ::: "memory");

        const unsigned short* buf = &lds[(it & 1) * 16384];

        FragU ahi[2], alo[2];
        #pragma unroll
        for (int i = 0; i < 2; ++i) {
            #pragma unroll
            for (int h = 0; h < 2; ++h) {
                float4 f = *(const float4*)(buf + aoff[i][h]);
                unsigned bx = __builtin_bit_cast(unsigned, f.x);
                unsigned by = __builtin_bit_cast(unsigned, f.y);
                unsigned bz = __builtin_bit_cast(unsigned, f.z);
                unsigned bw = __builtin_bit_cast(unsigned, f.w);
                ahi[i].u[h * 2]     = __builtin_amdgcn_perm(by, bx, 0x07060302);
                ahi[i].u[h * 2 + 1] = __builtin_amdgcn_perm(bw, bz, 0x07060302);
                float lx = f.x - __builtin_bit_cast(float, bx & 0xFFFF0000u);
                float ly = f.y - __builtin_bit_cast(float, by & 0xFFFF0000u);
                float lz = f.z - __builtin_bit_cast(float, bz & 0xFFFF0000u);
                float lw = f.w - __builtin_bit_cast(float, bw & 0xFFFF0000u);
                alo[i].u[h * 2]     = __builtin_amdgcn_perm(
                    __builtin_bit_cast(unsigned, ly), __builtin_bit_cast(unsigned, lx), 0x07060302);
                alo[i].u[h * 2 + 1] = __builtin_amdgcn_perm(
                    __builtin_bit_cast(unsigned, lw), __builtin_bit_cast(unsigned, lz), 0x07060302);
            }
        }
        FragU bhi[4], blo[4];
        #pragma unroll
        for (int j = 0; j < 4; ++j) {
            bhi[j].v = *(const bf16x8*)(buf +  8192 + boff[j]);
            blo[j].v = *(const bf16x8*)(buf + 12288 + boff[j]);
        }
        #pragma unroll
        for (int i = 0; i < 2; ++i)
            #pragma unroll
            for (int j = 0; j < 4; ++j) {
                acc[i][j] = __builtin_amdgcn_mfma_f32_16x16x32_bf16(ahi[i].v, bhi[j].v, acc[i][j], 0, 0, 0);
                acc[i][j] = __builtin_amdgcn_mfma_f32_16x16x32_bf16(alo[i].v, bhi[j].v, acc[i][j], 0, 0, 0);
                acc[i][j] = __builtin_amdgcn_mfma_f32_16x16x32_bf16(ahi[i].v, blo[j].v, acc[i][j], 0, 0, 0);
            }
    }

    #pragma unroll
    for (int i = 0; i < 2; ++i) {
        #pragma unroll
        for (int reg = 0; reg < 4; ++reg) {
            int mg = m0 + wm + i * 16 + q * 4 + reg;
            float* dst = Cc + (size_t)mg * N_ + n0 + wn + r;
            dst[0]  = acc[i][0][reg];
            dst[16] = acc[i][1][reg];
            dst[32] = acc[i][2][reg];
            dst[48] = acc[i][3][reg];
        }
    }

    // fused scan phase A: carry[b][c][n] = sum_{row} a^(15-row) uB[row][n]
    {
        const int b  = m0 >> 12;
        const int c0 = ((m0 & 4095) + wm) >> 4;
        #pragma unroll
        for (int j = 0; j < 4; ++j) {
            const int n = n0 + wn + j * 16 + r;
            const float a  = Av[n];
            const float a2 = a * a, a3 = a2 * a, a4 = a2 * a2;
            const float a8 = a4 * a4, a12 = a8 * a4;
            const float base = (q == 0) ? a12 : (q == 1) ? a8 : (q == 2) ? a4 : 1.f;
            #pragma unroll
            for (int i = 0; i < 2; ++i) {
                float partial = base * (a3 * acc[i][j][0] + a2 * acc[i][j][1]
                                      + a  * acc[i][j][2] +      acc[i][j][3]);
                partial += __shfl_xor(partial, 16);
                partial += __shfl_xor(partial, 32);
                if (q == 0)
                    carry[((size_t)b * NC + (c0 + i)) * STATE + n] = partial;
            }
        }
    }
}

// ---------------------------------------------------------------------------
// Scan phase B, level 1: group-carry. Grid (BATCH, 16), 256 thr.
// Group g covers chunks [16g, 16g+16). All 16 carry rows batch-loaded
// (independent), then a 16-step local scan -> GC[b][g][n].
// Max serial chain: 16 fmas (vs 256 in the old scan_entries).
// ---------------------------------------------------------------------------
__global__ __launch_bounds__(256) void scan_gc(
    const float* __restrict__ carry, const float* __restrict__ A,
    float* __restrict__ GC)
{
    const int b = blockIdx.x, g = blockIdx.y, n = threadIdx.x;
    const float a = A[n];
    float aL = a;
    #pragma unroll
    for (int k = 0; k < 4; ++k) aL *= aL;     // a^16 = a^LC

    const float* cr = carry + ((size_t)b * NC + g * 16) * STATE + n;
    float v[16];
    #pragma unroll
    for (int i = 0; i < 16; ++i) v[i] = cr[(size_t)i * STATE];
    float s = 0.f;
    #pragma unroll
    for (int i = 0; i < 16; ++i) s = fmaf(aL, s, v[i]);
    GC[((size_t)b * 16 + g) * STATE + n] = s;
}

// ---------------------------------------------------------------------------
// Scan phase B, level 2: absolute entries. Grid (BATCH, 16), 256 thr.
// Group entry S = x0-seeded scan of GC[0..g) (<=15 fmas, independent loads),
// then re-scan the group's 16 carries writing entry[c] (state BEFORE chunk c).
// g==15 also writes x_last (final state). Exact linear regrouping of the old
// 256-step chain (reassociation-level rounding only).
// ---------------------------------------------------------------------------
__global__ __launch_bounds__(256) void scan_fix(
    const float* __restrict__ carry, const float* __restrict__ GC,
    const float* __restrict__ A, const float* __restrict__ x0,
    float* __restrict__ entry, float* __restrict__ x_last)
{
    const int b = blockIdx.x, g = blockIdx.y, n = threadIdx.x;
    const float a = A[n];
    float aL = a;
    #pragma unroll
    for (int k = 0; k < 4; ++k) aL *= aL;     // a^16
    float aG = aL;
    #pragma unroll
    for (int k = 0; k < 4; ++k) aG *= aG;     // a^256 (one group)

    // batch-load this group's carries early (16 independent loads in flight)
    const float* cr = carry + ((size_t)b * NC + g * 16) * STATE + n;
    float v[16];
    #pragma unroll
    for (int i = 0; i < 16; ++i) v[i] = cr[(size_t)i * STATE];

    // group-entry S: scan GC[0..g) seeded from x0
    float S = x0[(size_t)b * STATE + n];
    const float* gc = GC + (size_t)b * 16 * STATE + n;
    for (int gp = 0; gp < g; ++gp)
        S = fmaf(aG, S, gc[(size_t)gp * STATE]);

    float* en = entry + ((size_t)b * NC + g * 16) * STATE + n;
    float s = S;
    #pragma unroll
    for (int i = 0; i < 16; ++i) {
        en[(size_t)i * STATE] = s;
        s = fmaf(aL, s, v[i]);
    }
    if (g == 15) x_last[(size_t)b * STATE + n] = s;
}

// ---------------------------------------------------------------------------
// GEMM2 + fused scan phase C (unchanged from round 5).
// ---------------------------------------------------------------------------
__global__ __launch_bounds__(512, 4) void gemm_scan_apply(
    const float* __restrict__ uB, const unsigned short* __restrict__ Bthi,
    const unsigned short* __restrict__ Btlo, const float* __restrict__ Av,
    const float* __restrict__ entry, float* __restrict__ Cc,
    int N_, int K)
{
    __shared__ unsigned short lds[2 * 16384];   // 64 KB

    const int tid  = threadIdx.x;
    const int wave = tid >> 6;
    const int lane = tid & 63;
    const int n0 = blockIdx.x * 128;
    const int m0 = blockIdx.y * 128;
    const int bb_ = m0 >> 12;               // batch
    const int c0_ = (m0 & 4095) >> 4;       // first chunk of this m-band

    const char* gp[4];
    int ldsoff[4], gstep[4];
    #pragma unroll
    for (int t = 0; t < 4; ++t) {
        int gi = wave * 4 + t;
        if (gi < 16) {          // uB fp32 plane: 16 KB
            int p = gi * 64 + lane;
            int row = p >> 3, s = p & 7;
            int l = s ^ (row & 7);
            gp[t] = (const char*)(uB + (size_t)(m0 + row) * K + l * 4);
            gstep[t] = 32 * 4;
            ldsoff[t] = gi * 512;
        } else {                // Ct hi/lo planes: 8 KB each
            int q2 = (gi - 16) >> 3;
            int pi = gi & 7;
            int p = pi * 64 + lane;
            int row = p >> 2, s = p & 3;
            int l = s ^ ((row >> 1) & 3);
            const unsigned short* base = q2 ? Btlo : Bthi;
            gp[t] = (const char*)(base + (size_t)(n0 + row) * K + l * 8);
            gstep[t] = 32 * 2;
            ldsoff[t] = 8192 + q2 * 4096 + pi * 512;
        }
    }

    const int r = lane & 15, q = lane >> 4;
    const int wm = (wave >> 1) * 32, wn = (wave & 1) * 64;

    int aoff[2][2], boff[4];
    #pragma unroll
    for (int i = 0; i < 2; ++i) {
        int row = wm + i * 16 + r;
        #pragma unroll
        for (int h = 0; h < 2; ++h)
            aoff[i][h] = row * 64 + ((2 * q + h) ^ (row & 7)) * 8;
    }
    #pragma unroll
    for (int j = 0; j < 4; ++j) {
        int row = wn + j * 16 + r;
        boff[j] = row * 32 + (q ^ ((row >> 1) & 3)) * 8;
    }

    // scan task: chunk sc (16 rows), state column sk (within BK)
    const int sc = tid >> 5;                // 0..15 (only <8 used)
    const int sk = tid & 31;

    f32x4 acc[2][4];
    #pragma unroll
    for (int i = 0; i < 2; ++i)
        #pragma unroll
        for (int j = 0; j < 4; ++j)
            acc[i][j] = (f32x4){0.f, 0.f, 0.f, 0.f};

    #pragma unroll
    for (int t = 0; t < 4; ++t) {
        __builtin_amdgcn_global_load_lds(
            (const __attribute__((address_space(1))) unsigned*)(gp[t]),
            (__attribute__((address_space(3))) unsigned*)(&lds[ldsoff[t]]),
            16, 0, 0);
        gp[t] += gstep[t];
    }

    const int nit = K >> 5;   // 8
    for (int it = 0; it < nit; ++it) {
        asm volatile("" ::: "memory");
        __builtin_amdgcn_s_barrier();
        asm volatile("" ::: "memory");
        if (it + 1 < nit) {
            const int bb = ((it + 1) & 1) * 16384;
            #pragma unroll
            for (int t = 0; t < 4; ++t) {
                __builtin_amdgcn_global_load_lds(
                    (const __attribute__((address_space(1))) unsigned*)(gp[t]),
                    (__attribute__((address_space(3))) unsigned*)(&lds[bb + ldsoff[t]]),
                    16, 0, 0);
                gp[t] += gstep[t];
            }
            __builtin_amdgcn_s_waitcnt(0x0F74);   // vmcnt(4)
        } else {
            __builtin_amdgcn_s_waitcnt(0x0F70);   // vmcnt(0)
        }
        asm volatile("" ::: "memory");
        __builtin_amdgcn_s_barrier();
        asm volatile("" ::: "memory");

        unsigned short* bufw = &lds[(it & 1) * 16384];
        const unsigned short* buf = bufw;

        // ---- fused scan phase C: uB tile -> x tile, in place (fp32) ----
        if (tid < 256) {
            const int kg = it * 32 + sk;
            const float a = Av[kg];
            float s = entry[((size_t)bb_ * NC + (c0_ + sc)) * STATE + kg];
            #pragma unroll
            for (int j = 0; j < 16; ++j) {
                int row = sc * 16 + j;
                int off = row * 64 + (((sk >> 2) ^ (row & 7)) * 8) + ((sk & 3) * 2);
                float v = *(const float*)(bufw + off);
                s = fmaf(a, s, v);
                *(float*)(bufw + off) = s;
            }
        }
        asm volatile("s_waitcnt lgkmcnt(0)" ::: "memory");
        __builtin_amdgcn_s_barrier();
        asm volatile("" ::: "memory");

        // ---- MFMA path: in-register fp32 -> hi/lo split on x ----
        FragU ahi[2], alo[2];
        #pragma unroll
        for (int i = 0; i < 2; ++i) {
            #pragma unroll
            for (int h = 0; h < 2; ++h) {
                float4 f = *(const float4*)(buf + aoff[i][h]);
                unsigned bx = __builtin_bit_cast(unsigned, f.x);
                unsigned by = __builtin_bit_cast(unsigned, f.y);
                unsigned bz = __builtin_bit_cast(unsigned, f.z);
                unsigned bw = __builtin_bit_cast(unsigned, f.w);
                ahi[i].u[h * 2]     = __builtin_amdgcn_perm(by, bx, 0x07060302);
                ahi[i].u[h * 2 + 1] = __builtin_amdgcn_perm(bw, bz, 0x07060302);
                float lx = f.x - __builtin_bit_cast(float, bx & 0xFFFF0000u);
                float ly = f.y - __builtin_bit_cast(float, by & 0xFFFF0000u);
                float lz = f.z - __builtin_bit_cast(float, bz & 0xFFFF0000u);
                float lw = f.w - __builtin_bit_cast(float, bw & 0xFFFF0000u);
                alo[i].u[h * 2]     = __builtin_amdgcn_perm(
                    __builtin_bit_cast(unsigned, ly), __builtin_bit_cast(unsigned, lx), 0x07060302);
                alo[i].u[h * 2 + 1] = __builtin_amdgcn_perm(
                    __builtin_bit_cast(unsigned, lw), __builtin_bit_cast(unsigned, lz), 0x07060302);
            }
        }
        FragU bhi[4], blo[4];
        #pragma unroll
        for (int j = 0; j < 4; ++j) {
            bhi[j].v = *(const bf16x8*)(buf +  8192 + boff[j]);
            blo[j].v = *(const bf16x8*)(buf + 12288 + boff[j]);
        }
        #pragma unroll
        for (int i = 0; i < 2; ++i)
            #pragma unroll
            for (int j = 0; j < 4; ++j) {
                acc[i][j] = __builtin_amdgcn_mfma_f32_16x16x32_bf16(ahi[i].v, bhi[j].v, acc[i][j], 0, 0, 0);
                acc[i][j] = __builtin_amdgcn_mfma_f32_16x16x32_bf16(alo[i].v, bhi[j].v, acc[i][j], 0, 0, 0);
                acc[i][j] = __builtin_amdgcn_mfma_f32_16x16x32_bf16(ahi[i].v, blo[j].v, acc[i][j], 0, 0, 0);
            }
    }

    #pragma unroll
    for (int i = 0; i < 2; ++i) {
        #pragma unroll
        for (int reg = 0; reg < 4; ++reg) {
            int mg = m0 + wm + i * 16 + q * 4 + reg;
            float* dst = Cc + (size_t)mg * N_ + n0 + wn + r;
            dst[0]  = acc[i][0][reg];
            dst[16] = acc[i][1][reg];
            dst[32] = acc[i][2][reg];
            dst[48] = acc[i][3][reg];
        }
    }
}

// ---------------------------------------------------------------------------
extern "C" void kernel_launch(void* const* d_in, const int* in_sizes, int n_in,
                              void* d_out, int out_size, void* d_ws, size_t ws_size,
                              hipStream_t stream)
{
    const float* u  = (const float*)d_in[0];   // [8,4096,512]
    const float* x0 = (const float*)d_in[1];   // [8,256]
    const float* A  = (const float*)d_in[2];   // [256]
    const float* B  = (const float*)d_in[3];   // [512,256]
    const float* C  = (const float*)d_in[4];   // [256,512]

    const size_t MB = 1024 * 1024;
    char* ws = (char*)d_ws;

    float* uB    = (float*)(ws);                // [M,256] fp32, 32 MB
    float* carry = (float*)(ws + 32 * MB);      // [8,256,256] fp32, 2 MB
    float* entry = (float*)(ws + 34 * MB);      // [8,256,256] fp32, 2 MB
    float* GC    = (float*)(ws + 36 * MB);      // [8,16,256]  fp32, 128 KB
    unsigned short* Bt_hi = (unsigned short*)(ws + 36 * MB + 128 * 1024);   // 256 KB
    unsigned short* Bt_lo = (unsigned short*)(ws + 36 * MB + 384 * 1024);   // 256 KB
    unsigned short* Ct_hi = (unsigned short*)(ws + 36 * MB + 640 * 1024);   // 256 KB
    unsigned short* Ct_lo = (unsigned short*)(ws + 36 * MB + 896 * 1024);   // 256 KB

    float* y      = (float*)d_out;                             // [8,4096,512] = 64 MB
    float* x_last = y + (size_t)BATCH * LENGTH * OUT_DIM;      // [8,256]

    const int M = BATCH * LENGTH;   // 32768

    // 1. split+transpose both weights to bf16 hi/lo planes
    split_weights<<<dim3((IN_DIM * STATE + STATE * OUT_DIM) / 256), dim3(256), 0, stream>>>(
        B, C, Bt_hi, Bt_lo, Ct_hi, Ct_lo);

    // 2. GEMM1 (+fused scan phase A): uB = u @ B, carry per 16-row chunk
    gemm_dbuf<<<dim3(STATE / 128, M / 128), dim3(512), 0, stream>>>(
        u, Bt_hi, Bt_lo, uB, A, carry, STATE, IN_DIM);

    // 3. two-level parallel entry scan (128 blocks each, chain <= 31 steps)
    scan_gc <<<dim3(BATCH, 16), dim3(256), 0, stream>>>(carry, A, GC);
    scan_fix<<<dim3(BATCH, 16), dim3(256), 0, stream>>>(carry, GC, A, x0, entry, x_last);

    // 4. GEMM2 (+fused scan phase C): y = scan(uB) @ C, x never materialized
    gemm_scan_apply<<<dim3(OUT_DIM / 128, M / 128), dim3(512), 0, stream>>>(
        uB, Ct_hi, Ct_lo, A, entry, y, OUT_DIM, STATE);
}